// Round 2
// baseline (547.055 us; speedup 1.0000x reference)
//
#include <hip/hip_runtime.h>
#include <hip/hip_bf16.h>

#define DIM   512
#define NH    8
#define HDIM  64
#define TDIM  64     // time features = 2*TDIM = 128
#define LIND  1536
#define LSEQ  2048
#define BB    2
#define ROWS  (BB*LSEQ)   // 4096
#define TF    128         // 2*TDIM

// ---------------- time features: time[l][h][0:128] ----------------
__global__ __launch_bounds__(256) void time_kernel(const float* __restrict__ tang,
                                                   const float* __restrict__ htd,
                                                   float* __restrict__ timef)
{
    int idx = blockIdx.x * 256 + threadIdx.x;     // < LSEQ*NH*TDIM = 1048576
    int d = idx & 63;
    int h = (idx >> 6) & 7;
    int l = idx >> 9;
    float ang = ((float)l + htd[h]) * tang[h * TDIM + d];
    float s, c;
    sincosf(ang, &s, &c);
    float* p = timef + ((size_t)l * NH + h) * TF;
    p[d]      = (c + s) * 0.125f;   // 1/sqrt(64)
    p[d + 64] = (c - s) * 0.125f;
}

// ---------------- generic 64x64 tiled GEMM, f32 accumulate ----------------
// C[M,N] = epilogue(A[M,K] @ B[K,N])
// EPI: 0 = sigmoid(x - exp(bias))/64   (Q gate)
//      1 = x + bias                    (V)
//      2 = x + bias + res              (O + residual tensor)
//      3 = gelu_tanh(x + bias)         (FFN in)
//      4 = x + bias + res              (FFN out + residual inter)
template<int EPI>
__global__ __launch_bounds__(256) void gemm64(const float* __restrict__ A,
                                              const float* __restrict__ B,
                                              const float* __restrict__ bias,
                                              const float* __restrict__ res,
                                              float* __restrict__ C,
                                              int M, int N, int K)
{
    __shared__ float As[16][65];
    __shared__ float Bs[16][65];
    int tid = threadIdx.x;
    int tx = tid & 15, ty = tid >> 4;
    int bm = blockIdx.y * 64, bn = blockIdx.x * 64;

    float acc[4][4] = {};
    for (int kt = 0; kt < K; kt += 16) {
        {   // A tile: 64 rows x 16 k, As[k][m]
            int k = tid & 15, m0 = tid >> 4;
            #pragma unroll
            for (int r = 0; r < 4; ++r) {
                int m = m0 + 16 * r;
                As[k][m] = A[(size_t)(bm + m) * K + kt + k];
            }
        }
        {   // B tile: 16 k x 64 cols, Bs[k][n]
            int n = tid & 63, k0 = tid >> 6;
            #pragma unroll
            for (int r = 0; r < 4; ++r) {
                int k = k0 + 4 * r;
                Bs[k][n] = B[(size_t)(kt + k) * N + bn + n];
            }
        }
        __syncthreads();
        #pragma unroll
        for (int k = 0; k < 16; ++k) {
            float a[4], b[4];
            #pragma unroll
            for (int i = 0; i < 4; ++i) a[i] = As[k][ty * 4 + i];
            #pragma unroll
            for (int j = 0; j < 4; ++j) b[j] = Bs[k][tx * 4 + j];
            #pragma unroll
            for (int i = 0; i < 4; ++i)
                #pragma unroll
                for (int j = 0; j < 4; ++j)
                    acc[i][j] = fmaf(a[i], b[j], acc[i][j]);
        }
        __syncthreads();
    }

    #pragma unroll
    for (int i = 0; i < 4; ++i) {
        int m = bm + ty * 4 + i;
        #pragma unroll
        for (int j = 0; j < 4; ++j) {
            int n = bn + tx * 4 + j;
            float x = acc[i][j];
            float bs = bias[n];
            float o;
            if constexpr (EPI == 0) {
                o = (1.0f / (1.0f + expf(-(x - expf(bs))))) * (1.0f / 64.0f);
            } else if constexpr (EPI == 1) {
                o = x + bs;
            } else if constexpr (EPI == 2) {
                o = x + bs + res[(size_t)m * N + n];
            } else if constexpr (EPI == 3) {
                float t = x + bs;
                float u = t + 0.044715f * t * t * t;
                o = 0.5f * t * (1.0f + tanhf(0.7978845608028654f * u));
            } else {
                o = x + bs + res[(size_t)m * N + n];
            }
            C[(size_t)m * N + n] = o;
        }
    }
}

// ---------------- W partials: Wpart[kc][b][h][d][hd] ----------------
// W[b,h,d,hd] = sum_t time[t,h,d] * v[b,t,h,hd], split-K over 16 chunks of 128
__global__ __launch_bounds__(256) void wpart_kernel(const float* __restrict__ v,
                                                    const float* __restrict__ timef,
                                                    float* __restrict__ wpart)
{
    int bh = blockIdx.x;          // 0..15
    int kc = blockIdx.y;          // 0..15
    int b = bh >> 3, h = bh & 7;
    int hd = threadIdx.x & 63, dg = threadIdx.x >> 6;   // dg 0..3

    float acc[32] = {};
    int t0 = kc * 128;
    for (int t = t0; t < t0 + 128; ++t) {
        float vv = v[((size_t)(b * LSEQ + t)) * DIM + h * HDIM + hd];
        const float* tp = timef + ((size_t)t * NH + h) * TF;
        #pragma unroll
        for (int k = 0; k < 32; ++k)
            acc[k] = fmaf(tp[dg + 4 * k], vv, acc[k]);
    }
    float* wp = wpart + ((size_t)(kc * 16 + bh)) * (TF * HDIM);
    #pragma unroll
    for (int k = 0; k < 32; ++k)
        wp[(dg + 4 * k) * HDIM + hd] = acc[k];
}

__global__ __launch_bounds__(256) void wred_kernel(const float* __restrict__ wpart,
                                                   float* __restrict__ W)
{
    int i = blockIdx.x * 256 + threadIdx.x;   // < 16*128*64 = 131072
    float s = 0.f;
    #pragma unroll
    for (int kc = 0; kc < 16; ++kc)
        s += wpart[(size_t)kc * 131072 + i];
    W[i] = s;
}

// ---------------- comb[b,l,h,hd] = qsum * sum_d time[l,h,d]*W[b,h,d,hd] ----
__global__ __launch_bounds__(256) void comb_kernel(const float* __restrict__ qraw,
                                                   const float* __restrict__ mask,
                                                   const float* __restrict__ timef,
                                                   const float* __restrict__ W,
                                                   float* __restrict__ comb)
{
    int idx = blockIdx.x * 256 + threadIdx.x;  // < ROWS*NH*HDIM = 2097152
    int hd = idx & 63;
    int g  = idx >> 6;          // (row, h)
    int h  = g & 7;
    int row = g >> 3;           // b*LSEQ + l
    int l = row & (LSEQ - 1);
    int b = row >> 11;

    // wave-reduce qraw over the 64 hd lanes -> qsum
    float q = qraw[(size_t)row * DIM + h * HDIM + hd];
    #pragma unroll
    for (int off = 1; off < 64; off <<= 1) q += __shfl_xor(q, off);
    q *= mask[row];

    const float* tp = timef + ((size_t)l * NH + h) * TF;
    const float* wp = W + ((size_t)(b * NH + h)) * (TF * HDIM);
    float acc = 0.f;
    #pragma unroll 8
    for (int d = 0; d < TF; ++d)
        acc = fmaf(tp[d], wp[d * HDIM + hd], acc);
    comb[(size_t)row * DIM + h * HDIM + hd] = q * acc;
}

// ---------------- LayerNorm over last dim (512) ----------------
__global__ __launch_bounds__(256) void ln_kernel(const float* __restrict__ X,
                                                 const float* __restrict__ g,
                                                 const float* __restrict__ bta,
                                                 float* __restrict__ outf)
{
    int row = blockIdx.x;
    const float* x = X + (size_t)row * DIM;
    float v0 = x[threadIdx.x], v1 = x[threadIdx.x + 256];
    float s = v0 + v1, s2 = v0 * v0 + v1 * v1;
    #pragma unroll
    for (int off = 1; off < 64; off <<= 1) {
        s  += __shfl_xor(s,  off);
        s2 += __shfl_xor(s2, off);
    }
    __shared__ float sh[2][4];
    int wave = threadIdx.x >> 6, lane = threadIdx.x & 63;
    if (lane == 0) { sh[0][wave] = s; sh[1][wave] = s2; }
    __syncthreads();
    s  = sh[0][0] + sh[0][1] + sh[0][2] + sh[0][3];
    s2 = sh[1][0] + sh[1][1] + sh[1][2] + sh[1][3];
    float mu  = s * (1.0f / DIM);
    float var = s2 * (1.0f / DIM) - mu * mu;
    float inv = rsqrtf(var + 1e-5f);
    int c0 = threadIdx.x, c1 = threadIdx.x + 256;
    outf[(size_t)row * DIM + c0] = (v0 - mu) * inv * g[c0] + bta[c0];
    outf[(size_t)row * DIM + c1] = (v1 - mu) * inv * g[c1] + bta[c1];
}

extern "C" void kernel_launch(void* const* d_in, const int* in_sizes, int n_in,
                              void* d_out, int out_size, void* d_ws, size_t ws_size,
                              hipStream_t stream)
{
    const float* tensor = (const float*)d_in[0];
    const float* mask   = (const float*)d_in[1];
    const float* tang   = (const float*)d_in[2];
    const float* htd    = (const float*)d_in[3];
    const float* Qw     = (const float*)d_in[4];
    const float* qb     = (const float*)d_in[5];
    // d_in[6], d_in[7] (Kw, Kb) are dead code in the reference
    const float* Vw     = (const float*)d_in[8];
    const float* Vb     = (const float*)d_in[9];
    const float* Ow     = (const float*)d_in[10];
    const float* Ob     = (const float*)d_in[11];
    const float* g1     = (const float*)d_in[12];
    const float* b1     = (const float*)d_in[13];
    const float* Win    = (const float*)d_in[14];
    const float* bin    = (const float*)d_in[15];
    const float* Wout   = (const float*)d_in[16];
    const float* bout   = (const float*)d_in[17];
    const float* g2     = (const float*)d_in[18];
    const float* b2     = (const float*)d_in[19];
    float* out = (float*)d_out;

    float* ws = (float*)d_ws;
    const size_t SZ = (size_t)ROWS * DIM;   // 2097152 floats
    float* timef = ws;             // [0 .. SZ)
    float* qraw  = ws + SZ;        // [SZ .. 2SZ)
    float* vbuf  = ws + 2 * SZ;    // v, then pre-LN1 (residual sum)
    float* inter = ws + 3 * SZ;    // LN1 output, alive until FFN2 residual
    float* buf5  = ws + 4 * SZ;    // comb, then pre-LN2
    float* wpart = ws + 5 * SZ;    // 16*131072 = SZ
    float* Wm    = ws + 6 * SZ;    // 131072
    float* act   = ws;             // FFN1 output [0 .. 3*SZ), reuses timef/qraw/vbuf (all dead)

    // 1. time features
    time_kernel<<<LSEQ * NH * TDIM / 256, 256, 0, stream>>>(tang, htd, timef);
    // 2. Q gate values: sigmoid(x@Qw - exp(qb))/64
    gemm64<0><<<dim3(DIM / 64, ROWS / 64), 256, 0, stream>>>(tensor, Qw, qb, nullptr, qraw, ROWS, DIM, DIM);
    // 3. V projection
    gemm64<1><<<dim3(DIM / 64, ROWS / 64), 256, 0, stream>>>(tensor, Vw, Vb, nullptr, vbuf, ROWS, DIM, DIM);
    // 4. W[b,h,d,hd] = sum_t time*v  (split-K)
    wpart_kernel<<<dim3(16, 16), 256, 0, stream>>>(vbuf, timef, wpart);
    wred_kernel<<<131072 / 256, 256, 0, stream>>>(wpart, Wm);
    // 5. comb
    comb_kernel<<<(ROWS * NH * HDIM) / 256, 256, 0, stream>>>(qraw, mask, timef, Wm, buf5);
    // 6. attn_out + residual (tensor)
    gemm64<2><<<dim3(DIM / 64, ROWS / 64), 256, 0, stream>>>(buf5, Ow, Ob, tensor, vbuf, ROWS, DIM, DIM);
    // 7. LN1 -> inter (f32)
    ln_kernel<<<ROWS, 256, 0, stream>>>(vbuf, g1, b1, inter);
    // 8. FFN in + gelu
    gemm64<3><<<dim3(LIND / 64, ROWS / 64), 256, 0, stream>>>(inter, Win, bin, nullptr, act, ROWS, LIND, DIM);
    // 9. FFN out + residual (inter)
    gemm64<4><<<dim3(DIM / 64, ROWS / 64), 256, 0, stream>>>(act, Wout, bout, inter, buf5, ROWS, DIM, LIND);
    // 10. LN2 -> f32 output
    ln_kernel<<<ROWS, 256, 0, stream>>>(buf5, g2, b2, out);
}

// Round 3
// 330.604 us; speedup vs baseline: 1.6547x; 1.6547x over previous
//
#include <hip/hip_runtime.h>
#include <hip/hip_bf16.h>

typedef __hip_bfloat16 bf16;
typedef __attribute__((ext_vector_type(8))) __bf16 bf16x8;
typedef __attribute__((ext_vector_type(4))) float f32x4;

#define DIM   512
#define NH    8
#define HDIM  64
#define TDIM  64
#define LIND  1536
#define LSEQ  2048
#define BB    2
#define ROWS  (BB*LSEQ)   // 4096
#define TF    128         // 2*TDIM

__device__ __forceinline__ float b2f(bf16 v){ return __bfloat162float(v); }
__device__ __forceinline__ void stc(float* C, size_t i, float v){ C[i] = v; }
__device__ __forceinline__ void stc(bf16*  C, size_t i, float v){ C[i] = __float2bfloat16(v); }

// ---------------- f32 -> bf16 convert (4 elems/thread) ----------------
__global__ __launch_bounds__(256) void cvt_kernel(const float* __restrict__ in,
                                                  bf16* __restrict__ out)
{
    int i = blockIdx.x * 256 + threadIdx.x;
    float4 v = ((const float4*)in)[i];
    bf16 t[4];
    t[0] = __float2bfloat16(v.x); t[1] = __float2bfloat16(v.y);
    t[2] = __float2bfloat16(v.z); t[3] = __float2bfloat16(v.w);
    *(uint2*)&out[(size_t)i * 4] = *(uint2*)t;
}

// ---------------- f32 [R][C] -> bf16 [C][R] transpose ----------------
__global__ __launch_bounds__(256) void transpose_kernel(const float* __restrict__ in,
                                                        bf16* __restrict__ out,
                                                        int R, int C)
{
    __shared__ float t[32][33];
    int bx = blockIdx.x * 32;   // C index
    int by = blockIdx.y * 32;   // R index
    int x = threadIdx.x & 31, y = threadIdx.x >> 5;   // y: 0..7
    #pragma unroll
    for (int r = 0; r < 32; r += 8)
        t[y + r][x] = in[(size_t)(by + y + r) * C + bx + x];
    __syncthreads();
    #pragma unroll
    for (int r = 0; r < 32; r += 8)
        out[(size_t)(bx + y + r) * R + by + x] = __float2bfloat16(t[x][y + r]);
}

// ---------------- time features (bf16): time[l][h][0:128] ----------------
__global__ __launch_bounds__(256) void time_kernel(const float* __restrict__ tang,
                                                   const float* __restrict__ htd,
                                                   bf16* __restrict__ timef)
{
    int idx = blockIdx.x * 256 + threadIdx.x;     // < LSEQ*NH*TDIM = 1048576
    int d = idx & 63;
    int h = (idx >> 6) & 7;
    int l = idx >> 9;
    float ang = ((float)l + htd[h]) * tang[h * TDIM + d];
    float s, c;
    sincosf(ang, &s, &c);
    bf16* p = timef + ((size_t)l * NH + h) * TF;
    p[d]      = __float2bfloat16((c + s) * 0.125f);   // 1/sqrt(64)
    p[d + 64] = __float2bfloat16((c - s) * 0.125f);
}

// ---------------- bf16 MFMA GEMM: C = epi(A[M,K] @ Bt[N,K]^T) ----------------
// 4 waves (2x2), wave tile 64 x (NREP*16), BM=128, BN=NREP*32, BK=32
// EPI: 0 sigmoid(x-exp(b))/64 | 1 x+b | 2 x+b+res | 3 gelu(x+b) | 4 x+b+res
template<int NREP, int EPI, typename OUTT>
__global__ __launch_bounds__(256) void gemm_mfma(const bf16* __restrict__ A,
                                                 const bf16* __restrict__ Bt,
                                                 const float* __restrict__ bias,
                                                 const float* __restrict__ res,
                                                 OUTT* __restrict__ C,
                                                 int M, int N, int K)
{
    constexpr int BN = NREP * 32;
    __shared__ unsigned short As[128 * 32];
    __shared__ unsigned short Bs[BN * 32];

    int tid  = threadIdx.x;
    int lane = tid & 63, wave = tid >> 6;
    int wr = wave >> 1, wc = wave & 1;
    int bm = blockIdx.y * 128, bn = blockIdx.x * BN;
    int l15 = lane & 15, lk = lane >> 4;   // lk: 0..3 (k-group)

    f32x4 acc[4][NREP] = {};

    for (int kt = 0; kt < K; kt += 32) {
        __syncthreads();
        #pragma unroll
        for (int p = 0; p < 2; ++p) {          // A tile: 128 rows x 32 k
            int e = p * 256 + tid;             // 0..511
            int row = e >> 2, kc = (e & 3) * 8;
            *(bf16x8*)&As[row * 32 + kc] =
                *(const bf16x8*)&A[(size_t)(bm + row) * K + kt + kc];
        }
        #pragma unroll
        for (int p = 0; p < BN / 64; ++p) {    // B tile: BN rows x 32 k
            int e = p * 256 + tid;
            int row = e >> 2, kc = (e & 3) * 8;
            *(bf16x8*)&Bs[row * 32 + kc] =
                *(const bf16x8*)&Bt[(size_t)(bn + row) * K + kt + kc];
        }
        __syncthreads();

        bf16x8 a[4], b[NREP];
        #pragma unroll
        for (int m = 0; m < 4; ++m)
            a[m] = *(const bf16x8*)&As[(wr * 64 + m * 16 + l15) * 32 + lk * 8];
        #pragma unroll
        for (int n = 0; n < NREP; ++n)
            b[n] = *(const bf16x8*)&Bs[(wc * NREP * 16 + n * 16 + l15) * 32 + lk * 8];
        #pragma unroll
        for (int m = 0; m < 4; ++m)
            #pragma unroll
            for (int n = 0; n < NREP; ++n)
                acc[m][n] = __builtin_amdgcn_mfma_f32_16x16x32_bf16(a[m], b[n], acc[m][n], 0, 0, 0);
    }

    #pragma unroll
    for (int m = 0; m < 4; ++m) {
        #pragma unroll
        for (int n = 0; n < NREP; ++n) {
            int gcol = bn + wc * NREP * 16 + n * 16 + l15;
            float bs = bias[gcol];
            #pragma unroll
            for (int r = 0; r < 4; ++r) {
                int grow = bm + wr * 64 + m * 16 + lk * 4 + r;
                float x = acc[m][n][r];
                float o;
                if constexpr (EPI == 0) {
                    o = (1.0f / (1.0f + expf(-(x - expf(bs))))) * (1.0f / 64.0f);
                } else if constexpr (EPI == 1) {
                    o = x + bs;
                } else if constexpr (EPI == 2) {
                    o = x + bs + res[(size_t)grow * N + gcol];
                } else if constexpr (EPI == 3) {
                    float t = x + bs;
                    float u = t + 0.044715f * t * t * t;
                    o = 0.5f * t * (1.0f + tanhf(0.7978845608028654f * u));
                } else {
                    o = x + bs + res[(size_t)grow * N + gcol];
                }
                stc(C, (size_t)grow * N + gcol, o);
            }
        }
    }
}

// ---------------- W partials: W[b,h,d,hd] = sum_t time[t,h,d]*v[b,t,h,hd] ----
// split-K over 8 chunks of 256
__global__ __launch_bounds__(256) void wpart_kernel(const float* __restrict__ v,
                                                    const bf16* __restrict__ timef,
                                                    float* __restrict__ wpart)
{
    int bh = blockIdx.x;          // 0..15
    int kc = blockIdx.y;          // 0..7
    int b = bh >> 3, h = bh & 7;
    int hd = threadIdx.x & 63, dg = threadIdx.x >> 6;   // dg 0..3

    float acc[32] = {};
    int t0 = kc * 256;
    for (int t = t0; t < t0 + 256; ++t) {
        float vv = v[((size_t)(b * LSEQ + t)) * DIM + h * HDIM + hd];
        const bf16* tp = timef + ((size_t)t * NH + h) * TF;
        #pragma unroll
        for (int k = 0; k < 32; ++k)
            acc[k] = fmaf(b2f(tp[dg + 4 * k]), vv, acc[k]);
    }
    float* wp = wpart + ((size_t)(kc * 16 + bh)) * (TF * HDIM);
    #pragma unroll
    for (int k = 0; k < 32; ++k)
        wp[(dg + 4 * k) * HDIM + hd] = acc[k];
}

__global__ __launch_bounds__(256) void wred_kernel(const float* __restrict__ wpart,
                                                   float* __restrict__ W)
{
    int i = blockIdx.x * 256 + threadIdx.x;   // < 16*128*64 = 131072
    float s = 0.f;
    #pragma unroll
    for (int kc = 0; kc < 8; ++kc)
        s += wpart[(size_t)kc * 131072 + i];
    W[i] = s;
}

// ---------------- comb[b,l,h,hd] = qsum * sum_d time[l,h,d]*W[b,h,d,hd] ----
__global__ __launch_bounds__(256) void comb_kernel(const bf16* __restrict__ qraw,
                                                   const float* __restrict__ mask,
                                                   const bf16* __restrict__ timef,
                                                   const float* __restrict__ W,
                                                   bf16* __restrict__ comb)
{
    int idx = blockIdx.x * 256 + threadIdx.x;  // < ROWS*NH*HDIM = 2097152
    int hd = idx & 63;
    int g  = idx >> 6;          // (row, h)
    int h  = g & 7;
    int row = g >> 3;           // b*LSEQ + l
    int l = row & (LSEQ - 1);
    int b = row >> 11;

    float q = b2f(qraw[(size_t)row * DIM + h * HDIM + hd]);
    #pragma unroll
    for (int off = 1; off < 64; off <<= 1) q += __shfl_xor(q, off);
    q *= mask[row];

    const bf16* tp  = timef + ((size_t)l * NH + h) * TF;
    const float* wp = W + ((size_t)(b * NH + h)) * (TF * HDIM);
    float acc = 0.f;
    #pragma unroll 8
    for (int d = 0; d < TF; ++d)
        acc = fmaf(b2f(tp[d]), wp[d * HDIM + hd], acc);
    comb[(size_t)row * DIM + h * HDIM + hd] = __float2bfloat16(q * acc);
}

// ---------------- LayerNorm over last dim (512) ----------------
template<int WB>
__global__ __launch_bounds__(256) void ln_kernel(const float* __restrict__ X,
                                                 const float* __restrict__ g,
                                                 const float* __restrict__ bta,
                                                 float* __restrict__ outf,
                                                 bf16* __restrict__ outb)
{
    int row = blockIdx.x;
    const float* x = X + (size_t)row * DIM;
    float v0 = x[threadIdx.x], v1 = x[threadIdx.x + 256];
    float s = v0 + v1, s2 = v0 * v0 + v1 * v1;
    #pragma unroll
    for (int off = 1; off < 64; off <<= 1) {
        s  += __shfl_xor(s,  off);
        s2 += __shfl_xor(s2, off);
    }
    __shared__ float sh[2][4];
    int wave = threadIdx.x >> 6, lane = threadIdx.x & 63;
    if (lane == 0) { sh[0][wave] = s; sh[1][wave] = s2; }
    __syncthreads();
    s  = sh[0][0] + sh[0][1] + sh[0][2] + sh[0][3];
    s2 = sh[1][0] + sh[1][1] + sh[1][2] + sh[1][3];
    float mu  = s * (1.0f / DIM);
    float var = s2 * (1.0f / DIM) - mu * mu;
    float inv = rsqrtf(var + 1e-5f);
    int c0 = threadIdx.x, c1 = threadIdx.x + 256;
    float o0 = (v0 - mu) * inv * g[c0] + bta[c0];
    float o1 = (v1 - mu) * inv * g[c1] + bta[c1];
    outf[(size_t)row * DIM + c0] = o0;
    outf[(size_t)row * DIM + c1] = o1;
    if constexpr (WB) {
        outb[(size_t)row * DIM + c0] = __float2bfloat16(o0);
        outb[(size_t)row * DIM + c1] = __float2bfloat16(o1);
    }
}

extern "C" void kernel_launch(void* const* d_in, const int* in_sizes, int n_in,
                              void* d_out, int out_size, void* d_ws, size_t ws_size,
                              hipStream_t stream)
{
    const float* tensor = (const float*)d_in[0];
    const float* mask   = (const float*)d_in[1];
    const float* tang   = (const float*)d_in[2];
    const float* htd    = (const float*)d_in[3];
    const float* Qw     = (const float*)d_in[4];
    const float* qb     = (const float*)d_in[5];
    // d_in[6], d_in[7] (Kw, Kb) dead code
    const float* Vw     = (const float*)d_in[8];
    const float* Vb     = (const float*)d_in[9];
    const float* Ow     = (const float*)d_in[10];
    const float* Ob     = (const float*)d_in[11];
    const float* g1     = (const float*)d_in[12];
    const float* b1     = (const float*)d_in[13];
    const float* Win    = (const float*)d_in[14];
    const float* bin    = (const float*)d_in[15];
    const float* Wout   = (const float*)d_in[16];
    const float* bout   = (const float*)d_in[17];
    const float* g2     = (const float*)d_in[18];
    const float* b2     = (const float*)d_in[19];
    float* out = (float*)d_out;

    float* ws = (float*)d_ws;
    // float-unit offsets; lifetimes verified step-by-step (total 43 MB)
    float* vbuf   = ws + 0;          // [0, 2097152)  f32: vbuf -> preLN1
    bf16*  actb   = (bf16*)(ws + 0); // [0, 3145728)  bf16 4096x1536 (steps 8-9)
    bf16*  tensorb= (bf16*)(ws + 2097152); // [2097152, 3145728): tensorb -> combb
    bf16*  combb  = tensorb;
    bf16*  timefb = (bf16*)(ws + 3145728); // [3145728, 4194304)
    float* wpart  = ws + 4194304;    // [4194304, 5242880): wpart -> interb
    bf16*  interb = (bf16*)(ws + 4194304);
    float* Wm     = ws + 5242880;    // [5242880, 5373952)
    bf16*  QwT    = (bf16*)(ws + 5373952);
    bf16*  VwT    = (bf16*)(ws + 5505024);
    bf16*  OwT    = (bf16*)(ws + 5636096);
    bf16*  WinT   = (bf16*)(ws + 5767168);
    bf16*  WoutT  = (bf16*)(ws + 6160384);
    bf16*  qrawb  = (bf16*)(ws + 6553600); // [6553600, 7602176): qraw; buf5 f32 overlays
    float* buf5   = ws + 6553600;    // [6553600, 8650752)
    float* inter  = ws + 8650752;    // [8650752, 10747904)

    // 0. precompute: bf16 casts / weight transposes / time features
    cvt_kernel<<<2048, 256, 0, stream>>>(tensor, tensorb);
    transpose_kernel<<<dim3(16, 16), 256, 0, stream>>>(Qw,  QwT,  DIM, DIM);
    transpose_kernel<<<dim3(16, 16), 256, 0, stream>>>(Vw,  VwT,  DIM, DIM);
    transpose_kernel<<<dim3(16, 16), 256, 0, stream>>>(Ow,  OwT,  DIM, DIM);
    transpose_kernel<<<dim3(48, 16), 256, 0, stream>>>(Win, WinT, DIM, LIND);
    transpose_kernel<<<dim3(16, 48), 256, 0, stream>>>(Wout, WoutT, LIND, DIM);
    time_kernel<<<4096, 256, 0, stream>>>(tang, htd, timefb);
    // 2. Q gate: sigmoid(x@Qw - exp(qb))/64 -> bf16
    gemm_mfma<2, 0, bf16><<<dim3(8, 32), 256, 0, stream>>>(tensorb, QwT, qb, nullptr, qrawb, ROWS, DIM, DIM);
    // 3. V projection -> f32
    gemm_mfma<2, 1, float><<<dim3(8, 32), 256, 0, stream>>>(tensorb, VwT, Vb, nullptr, vbuf, ROWS, DIM, DIM);
    // 4. W = sum_t time*v (split-K 8)
    wpart_kernel<<<dim3(16, 8), 256, 0, stream>>>(vbuf, timefb, wpart);
    wred_kernel<<<512, 256, 0, stream>>>(wpart, Wm);
    // 5. comb -> bf16
    comb_kernel<<<8192, 256, 0, stream>>>(qrawb, mask, timefb, Wm, combb);
    // 6. attn_out + residual(tensor) -> preLN1 (f32, reuses vbuf)
    gemm_mfma<2, 2, float><<<dim3(8, 32), 256, 0, stream>>>(combb, OwT, Ob, tensor, vbuf, ROWS, DIM, DIM);
    // 7. LN1 -> inter f32 + interb bf16
    ln_kernel<1><<<ROWS, 256, 0, stream>>>(vbuf, g1, b1, inter, interb);
    // 8. FFN in + gelu -> bf16 act
    gemm_mfma<4, 3, bf16><<<dim3(12, 32), 256, 0, stream>>>(interb, WinT, bin, nullptr, actb, ROWS, LIND, DIM);
    // 9. FFN out + residual(inter) -> buf5 f32
    gemm_mfma<2, 4, float><<<dim3(8, 32), 256, 0, stream>>>(actb, WoutT, bout, inter, buf5, ROWS, DIM, LIND);
    // 10. LN2 -> f32 output
    ln_kernel<0><<<ROWS, 256, 0, stream>>>(buf5, g2, b2, out, nullptr);
}

// Round 5
// 207.765 us; speedup vs baseline: 2.6330x; 1.5912x over previous
//
#include <hip/hip_runtime.h>
#include <hip/hip_bf16.h>

typedef __hip_bfloat16 bf16;
typedef __attribute__((ext_vector_type(8))) __bf16 bf16x8;
typedef __attribute__((ext_vector_type(4))) float f32x4;

#define DIM   512
#define NH    8
#define HDIM  64
#define TDIM  64
#define LIND  1536
#define LSEQ  2048
#define BB    2
#define ROWS  (BB*LSEQ)   // 4096
#define TF    128         // 2*TDIM
#define KCH   16          // wpart split-K chunks
#define TCH   128         // t per chunk (KCH*TCH = LSEQ)

__device__ __forceinline__ float b2f(bf16 v){ return __bfloat162float(v); }
__device__ __forceinline__ void stc(float* C, size_t i, float v){ C[i] = v; }
__device__ __forceinline__ void stc(bf16*  C, size_t i, float v){ C[i] = __float2bfloat16(v); }

typedef const __attribute__((address_space(1))) unsigned int* gp1_t;
typedef __attribute__((address_space(3))) unsigned int* lp3_t;
__device__ __forceinline__ void gload16(const bf16* g, unsigned short* l) {
    __builtin_amdgcn_global_load_lds((gp1_t)(const void*)g, (lp3_t)(void*)l, 16, 0, 0);
}

// ---------------- f32 -> bf16 convert (4 elems/thread) ----------------
__global__ __launch_bounds__(256) void cvt_kernel(const float* __restrict__ in,
                                                  bf16* __restrict__ out)
{
    int i = blockIdx.x * 256 + threadIdx.x;
    float4 v = ((const float4*)in)[i];
    bf16 t[4];
    t[0] = __float2bfloat16(v.x); t[1] = __float2bfloat16(v.y);
    t[2] = __float2bfloat16(v.z); t[3] = __float2bfloat16(v.w);
    *(uint2*)&out[(size_t)i * 4] = *(uint2*)t;
}

// ---------------- f32 [R][C] -> bf16 [C][R] transpose ----------------
__global__ __launch_bounds__(256) void transpose_kernel(const float* __restrict__ in,
                                                        bf16* __restrict__ out,
                                                        int R, int C)
{
    __shared__ float t[32][33];
    int bx = blockIdx.x * 32;   // C index
    int by = blockIdx.y * 32;   // R index
    int x = threadIdx.x & 31, y = threadIdx.x >> 5;   // y: 0..7
    #pragma unroll
    for (int r = 0; r < 32; r += 8)
        t[y + r][x] = in[(size_t)(by + y + r) * C + bx + x];
    __syncthreads();
    #pragma unroll
    for (int r = 0; r < 32; r += 8)
        out[(size_t)(bx + y + r) * R + by + x] = __float2bfloat16(t[x][y + r]);
}

// ---------------- time features (bf16): time[l][h][0:128] ----------------
__global__ __launch_bounds__(256) void time_kernel(const float* __restrict__ tang,
                                                   const float* __restrict__ htd,
                                                   bf16* __restrict__ timef)
{
    int idx = blockIdx.x * 256 + threadIdx.x;     // < LSEQ*NH*TDIM = 1048576
    int d = idx & 63;
    int h = (idx >> 6) & 7;
    int l = idx >> 9;
    float ang = ((float)l + htd[h]) * tang[h * TDIM + d];
    float s, c;
    sincosf(ang, &s, &c);
    bf16* p = timef + ((size_t)l * NH + h) * TF;
    p[d]      = __float2bfloat16((c + s) * 0.125f);   // 1/sqrt(64)
    p[d + 64] = __float2bfloat16((c - s) * 0.125f);
}

// ---------------- bf16 MFMA GEMM: C = epi(A[M,K] @ Bt[N,K]^T) ----------------
// 4 waves (2x2), wave tile 64 x (NREP*16), BM=128, BN=NREP*32, BK=32
// Staging via global_load_lds width-16 (LDS dest = uniform base + lane*16: ok).
template<int NREP, int EPI, typename OUTT>
__global__ __launch_bounds__(256) void gemm_mfma(const bf16* __restrict__ A,
                                                 const bf16* __restrict__ Bt,
                                                 const float* __restrict__ bias,
                                                 const float* __restrict__ res,
                                                 OUTT* __restrict__ C,
                                                 int M, int N, int K)
{
    constexpr int BN = NREP * 32;
    __shared__ unsigned short As[128 * 32];
    __shared__ unsigned short Bs[BN * 32];

    int tid  = threadIdx.x;
    int lane = tid & 63, wave = tid >> 6;
    int wr = wave >> 1, wc = wave & 1;
    int bm = blockIdx.y * 128, bn = blockIdx.x * BN;
    int l15 = lane & 15, lk = lane >> 4;   // lk: 0..3 (k-group)

    f32x4 acc[4][NREP] = {};

    for (int kt = 0; kt < K; kt += 32) {
        __syncthreads();
        #pragma unroll
        for (int p = 0; p < 2; ++p) {          // A tile: 128 rows x 32 k
            int e = p * 256 + tid;             // 0..511
            int row = e >> 2, kc = (e & 3) * 8;
            gload16(&A[(size_t)(bm + row) * K + kt + kc], &As[row * 32 + kc]);
        }
        #pragma unroll
        for (int p = 0; p < BN / 64; ++p) {    // B tile: BN rows x 32 k
            int e = p * 256 + tid;
            int row = e >> 2, kc = (e & 3) * 8;
            gload16(&Bt[(size_t)(bn + row) * K + kt + kc], &Bs[row * 32 + kc]);
        }
        __syncthreads();

        bf16x8 a[4], b[NREP];
        #pragma unroll
        for (int m = 0; m < 4; ++m)
            a[m] = *(const bf16x8*)&As[(wr * 64 + m * 16 + l15) * 32 + lk * 8];
        #pragma unroll
        for (int n = 0; n < NREP; ++n)
            b[n] = *(const bf16x8*)&Bs[(wc * NREP * 16 + n * 16 + l15) * 32 + lk * 8];
        #pragma unroll
        for (int m = 0; m < 4; ++m)
            #pragma unroll
            for (int n = 0; n < NREP; ++n)
                acc[m][n] = __builtin_amdgcn_mfma_f32_16x16x32_bf16(a[m], b[n], acc[m][n], 0, 0, 0);
    }

    #pragma unroll
    for (int m = 0; m < 4; ++m) {
        #pragma unroll
        for (int n = 0; n < NREP; ++n) {
            int gcol = bn + wc * NREP * 16 + n * 16 + l15;
            float bs = bias[gcol];
            #pragma unroll
            for (int r = 0; r < 4; ++r) {
                int grow = bm + wr * 64 + m * 16 + lk * 4 + r;
                float x = acc[m][n][r];
                float o;
                if constexpr (EPI == 0) {
                    o = (1.0f / (1.0f + expf(-(x - expf(bs))))) * (1.0f / 64.0f);
                } else if constexpr (EPI == 1) {
                    o = x + bs;
                } else if constexpr (EPI == 2) {
                    o = x + bs + res[(size_t)grow * N + gcol];
                } else if constexpr (EPI == 3) {
                    float t = x + bs;
                    float u = t + 0.044715f * t * t * t;
                    o = 0.5f * t * (1.0f + tanhf(0.7978845608028654f * u));
                } else {
                    o = x + bs + res[(size_t)grow * N + gcol];
                }
                stc(C, (size_t)grow * N + gcol, o);
            }
        }
    }
}

// ---------------- W partials: W[b,h,d,hd] = sum_t time[t,h,d]*v[b,t,h,hd] ----
// split-K over KCH chunks of TCH; thread owns contiguous 32-d block (vector loads)
__global__ __launch_bounds__(256) void wpart_kernel(const float* __restrict__ v,
                                                    const bf16* __restrict__ timef,
                                                    float* __restrict__ wpart)
{
    int bh = blockIdx.x;          // 0..15
    int kc = blockIdx.y;          // 0..KCH-1
    int b = bh >> 3, h = bh & 7;
    int hd = threadIdx.x & 63, dg = threadIdx.x >> 6;   // dg 0..3 -> d in [dg*32, dg*32+32)

    float acc[32] = {};
    int t0 = kc * TCH;
    for (int t = t0; t < t0 + TCH; ++t) {
        float vv = v[((size_t)(b * LSEQ + t)) * DIM + h * HDIM + hd];
        const bf16* tp = timef + ((size_t)t * NH + h) * TF + dg * 32;
        bf16x8 tv[4];
        #pragma unroll
        for (int q = 0; q < 4; ++q) tv[q] = *(const bf16x8*)&tp[q * 8];
        #pragma unroll
        for (int q = 0; q < 4; ++q)
            #pragma unroll
            for (int j = 0; j < 8; ++j)
                acc[q * 8 + j] = fmaf((float)tv[q][j], vv, acc[q * 8 + j]);
    }
    float* wp = wpart + ((size_t)(kc * 16 + bh)) * (TF * HDIM);
    #pragma unroll
    for (int q = 0; q < 4; ++q)
        #pragma unroll
        for (int j = 0; j < 8; ++j)
            wp[(dg * 32 + q * 8 + j) * HDIM + hd] = acc[q * 8 + j];
}

__global__ __launch_bounds__(256) void wred_kernel(const float* __restrict__ wpart,
                                                   float* __restrict__ W)
{
    int i = blockIdx.x * 256 + threadIdx.x;   // < 16*128*64 = 131072
    float s = 0.f;
    #pragma unroll
    for (int kc = 0; kc < KCH; ++kc)
        s += wpart[(size_t)kc * 131072 + i];
    W[i] = s;
}

// ---------------- comb[b,l,h,hd] = qsum * sum_d time[l,h,d]*W[b,h,d,hd] ----
__global__ __launch_bounds__(256) void comb_kernel(const bf16* __restrict__ qraw,
                                                   const float* __restrict__ mask,
                                                   const bf16* __restrict__ timef,
                                                   const float* __restrict__ W,
                                                   bf16* __restrict__ comb)
{
    int idx = blockIdx.x * 256 + threadIdx.x;  // < ROWS*NH*HDIM = 2097152
    int hd = idx & 63;
    int g  = idx >> 6;          // (row, h)
    int h  = g & 7;
    int row = g >> 3;           // b*LSEQ + l
    int l = row & (LSEQ - 1);
    int b = row >> 11;

    float q = b2f(qraw[(size_t)row * DIM + h * HDIM + hd]);
    #pragma unroll
    for (int off = 1; off < 64; off <<= 1) q += __shfl_xor(q, off);
    q *= mask[row];

    const bf16* tp  = timef + ((size_t)l * NH + h) * TF;
    const float* wp = W + ((size_t)(b * NH + h)) * (TF * HDIM);
    float acc = 0.f;
    #pragma unroll 8
    for (int d = 0; d < TF; ++d)
        acc = fmaf(b2f(tp[d]), wp[d * HDIM + hd], acc);
    comb[(size_t)row * DIM + h * HDIM + hd] = __float2bfloat16(q * acc);
}

// ---------------- LayerNorm over last dim (512) ----------------
template<int WB>
__global__ __launch_bounds__(256) void ln_kernel(const float* __restrict__ X,
                                                 const float* __restrict__ g,
                                                 const float* __restrict__ bta,
                                                 float* __restrict__ outf,
                                                 bf16* __restrict__ outb)
{
    int row = blockIdx.x;
    const float* x = X + (size_t)row * DIM;
    float v0 = x[threadIdx.x], v1 = x[threadIdx.x + 256];
    float s = v0 + v1, s2 = v0 * v0 + v1 * v1;
    #pragma unroll
    for (int off = 1; off < 64; off <<= 1) {
        s  += __shfl_xor(s,  off);
        s2 += __shfl_xor(s2, off);
    }
    __shared__ float sh[2][4];
    int wave = threadIdx.x >> 6, lane = threadIdx.x & 63;
    if (lane == 0) { sh[0][wave] = s; sh[1][wave] = s2; }
    __syncthreads();
    s  = sh[0][0] + sh[0][1] + sh[0][2] + sh[0][3];
    s2 = sh[1][0] + sh[1][1] + sh[1][2] + sh[1][3];
    float mu  = s * (1.0f / DIM);
    float var = s2 * (1.0f / DIM) - mu * mu;
    float inv = rsqrtf(var + 1e-5f);
    int c0 = threadIdx.x, c1 = threadIdx.x + 256;
    float o0 = (v0 - mu) * inv * g[c0] + bta[c0];
    float o1 = (v1 - mu) * inv * g[c1] + bta[c1];
    outf[(size_t)row * DIM + c0] = o0;
    outf[(size_t)row * DIM + c1] = o1;
    if constexpr (WB) {
        outb[(size_t)row * DIM + c0] = __float2bfloat16(o0);
        outb[(size_t)row * DIM + c1] = __float2bfloat16(o1);
    }
}

extern "C" void kernel_launch(void* const* d_in, const int* in_sizes, int n_in,
                              void* d_out, int out_size, void* d_ws, size_t ws_size,
                              hipStream_t stream)
{
    const float* tensor = (const float*)d_in[0];
    const float* mask   = (const float*)d_in[1];
    const float* tang   = (const float*)d_in[2];
    const float* htd    = (const float*)d_in[3];
    const float* Qw     = (const float*)d_in[4];
    const float* qb     = (const float*)d_in[5];
    // d_in[6], d_in[7] (Kw, Kb) dead code
    const float* Vw     = (const float*)d_in[8];
    const float* Vb     = (const float*)d_in[9];
    const float* Ow     = (const float*)d_in[10];
    const float* Ob     = (const float*)d_in[11];
    const float* g1     = (const float*)d_in[12];
    const float* b1     = (const float*)d_in[13];
    const float* Win    = (const float*)d_in[14];
    const float* bin    = (const float*)d_in[15];
    const float* Wout   = (const float*)d_in[16];
    const float* bout   = (const float*)d_in[17];
    const float* g2     = (const float*)d_in[18];
    const float* b2     = (const float*)d_in[19];
    float* out = (float*)d_out;

    float* ws = (float*)d_ws;
    // f32-unit offsets. Lifetimes (step written -> last step read):
    //   vbuf    [0,        2097152)  v: s3->s4        preLN1: s6->s7
    //   actb    [0,        3145728)  bf16 4096x1536:  s8->s9   (vbuf/tensorb dead)
    //   tensorb [2097152,  3145728)  s0->s3; combb reuse: s5->s6
    //   timefb  [3145728,  4194304)  s1->s5
    //   qrawb   [4194304,  5242880)  s2->s5
    //   wpart   [5242880,  7340032)  s4->s4.5; buf5 reuse (preLN2): s9->s10
    //   interb  [7340032,  8388608)  s7->s8
    //   Wm      [8388608,  8519680)  s4.5->s5
    //   QwT     [8519680,  8650752)  s0->s2
    //   VwT     [8650752,  8781824)  s0->s3
    //   OwT     [8781824,  8912896)  s0->s6
    //   WinT    [8912896,  9306112)  s0->s8
    //   WoutT   [9306112,  9699328)  s0->s9
    //   inter   [9699328, 11796480)  s7->s9
    // peak = 11796480 f32 = 47.2 MB (< 49.3 MB proven in round 3)
    float* vbuf   = ws + 0;
    bf16*  actb   = (bf16*)(ws + 0);
    bf16*  tensorb= (bf16*)(ws + 2097152);
    bf16*  combb  = tensorb;
    bf16*  timefb = (bf16*)(ws + 3145728);
    bf16*  qrawb  = (bf16*)(ws + 4194304);
    float* wpart  = ws + 5242880;
    float* buf5   = ws + 5242880;
    bf16*  interb = (bf16*)(ws + 7340032);
    float* Wm     = ws + 8388608;
    bf16*  QwT    = (bf16*)(ws + 8519680);
    bf16*  VwT    = (bf16*)(ws + 8650752);
    bf16*  OwT    = (bf16*)(ws + 8781824);
    bf16*  WinT   = (bf16*)(ws + 8912896);
    bf16*  WoutT  = (bf16*)(ws + 9306112);
    float* inter  = ws + 9699328;

    // 0. precompute: bf16 casts / weight transposes / time features
    cvt_kernel<<<2048, 256, 0, stream>>>(tensor, tensorb);
    transpose_kernel<<<dim3(16, 16), 256, 0, stream>>>(Qw,  QwT,  DIM, DIM);
    transpose_kernel<<<dim3(16, 16), 256, 0, stream>>>(Vw,  VwT,  DIM, DIM);
    transpose_kernel<<<dim3(16, 16), 256, 0, stream>>>(Ow,  OwT,  DIM, DIM);
    transpose_kernel<<<dim3(48, 16), 256, 0, stream>>>(Win, WinT, DIM, LIND);
    transpose_kernel<<<dim3(16, 48), 256, 0, stream>>>(Wout, WoutT, LIND, DIM);
    time_kernel<<<4096, 256, 0, stream>>>(tang, htd, timefb);
    // 2. Q gate: sigmoid(x@Qw - exp(qb))/64 -> bf16
    gemm_mfma<2, 0, bf16><<<dim3(8, 32), 256, 0, stream>>>(tensorb, QwT, qb, nullptr, qrawb, ROWS, DIM, DIM);
    // 3. V projection -> f32
    gemm_mfma<2, 1, float><<<dim3(8, 32), 256, 0, stream>>>(tensorb, VwT, Vb, nullptr, vbuf, ROWS, DIM, DIM);
    // 4. W = sum_t time*v (split-K 16)
    wpart_kernel<<<dim3(16, KCH), 256, 0, stream>>>(vbuf, timefb, wpart);
    wred_kernel<<<512, 256, 0, stream>>>(wpart, Wm);
    // 5. comb -> bf16
    comb_kernel<<<8192, 256, 0, stream>>>(qrawb, mask, timefb, Wm, combb);
    // 6. attn_out + residual(tensor) -> preLN1 (f32, reuses vbuf)
    gemm_mfma<2, 2, float><<<dim3(8, 32), 256, 0, stream>>>(combb, OwT, Ob, tensor, vbuf, ROWS, DIM, DIM);
    // 7. LN1 -> inter f32 + interb bf16
    ln_kernel<1><<<ROWS, 256, 0, stream>>>(vbuf, g1, b1, inter, interb);
    // 8. FFN in + gelu -> bf16 act
    gemm_mfma<4, 3, bf16><<<dim3(12, 32), 256, 0, stream>>>(interb, WinT, bin, nullptr, actb, ROWS, LIND, DIM);
    // 9. FFN out + residual(inter) -> buf5 f32
    gemm_mfma<2, 4, float><<<dim3(8, 32), 256, 0, stream>>>(actb, WoutT, bout, inter, buf5, ROWS, DIM, LIND);
    // 10. LN2 -> f32 output
    ln_kernel<0><<<ROWS, 256, 0, stream>>>(buf5, g2, b2, out, nullptr);
}

// Round 6
// 174.980 us; speedup vs baseline: 3.1264x; 1.1874x over previous
//
#include <hip/hip_runtime.h>
#include <hip/hip_bf16.h>

typedef __hip_bfloat16 bf16;
typedef __attribute__((ext_vector_type(8))) __bf16 bf16x8;
typedef __attribute__((ext_vector_type(4))) float f32x4;

#define DIM   512
#define NH    8
#define HDIM  64
#define LIND  1536
#define LSEQ  2048
#define ROWS  4096        // B*L
#define TF    128         // time features
#define KCH   16          // wpart split-K chunks
#define TCH   128         // t per chunk

__device__ __forceinline__ float b2f(bf16 v){ return __bfloat162float(v); }
__device__ __forceinline__ void stc(float* C, size_t i, float v){ C[i] = v; }
__device__ __forceinline__ void stc(bf16*  C, size_t i, float v){ C[i] = __float2bfloat16(v); }

typedef const __attribute__((address_space(1))) unsigned int* gp1_t;
typedef __attribute__((address_space(3))) unsigned int* lp3_t;
__device__ __forceinline__ void gload16(const bf16* g, unsigned short* l) {
    __builtin_amdgcn_global_load_lds((gp1_t)(const void*)g, (lp3_t)(void*)l, 16, 0, 0);
}

// ---------------- f32 -> bf16 convert (4 elems/thread) ----------------
__global__ __launch_bounds__(256) void cvt_kernel(const float* __restrict__ in,
                                                  bf16* __restrict__ out)
{
    int i = blockIdx.x * 256 + threadIdx.x;
    float4 v = ((const float4*)in)[i];
    bf16 t[4];
    t[0] = __float2bfloat16(v.x); t[1] = __float2bfloat16(v.y);
    t[2] = __float2bfloat16(v.z); t[3] = __float2bfloat16(v.w);
    *(uint2*)&out[(size_t)i * 4] = *(uint2*)t;
}

// ---------------- f32 [R][C] -> bf16 [C][R] transpose ----------------
__global__ __launch_bounds__(256) void transpose_kernel(const float* __restrict__ in,
                                                        bf16* __restrict__ out,
                                                        int R, int C)
{
    __shared__ float t[32][33];
    int bx = blockIdx.x * 32;   // C index
    int by = blockIdx.y * 32;   // R index
    int x = threadIdx.x & 31, y = threadIdx.x >> 5;   // y: 0..7
    #pragma unroll
    for (int r = 0; r < 32; r += 8)
        t[y + r][x] = in[(size_t)(by + y + r) * C + bx + x];
    __syncthreads();
    #pragma unroll
    for (int r = 0; r < 32; r += 8)
        out[(size_t)(bx + y + r) * R + by + x] = __float2bfloat16(t[x][y + r]);
}

// ---------------- time features (bf16): time[l][h][0:128] ----------------
__global__ __launch_bounds__(256) void time_kernel(const float* __restrict__ tang,
                                                   const float* __restrict__ htd,
                                                   bf16* __restrict__ timef)
{
    int idx = blockIdx.x * 256 + threadIdx.x;     // < LSEQ*NH*64 = 1048576
    int d = idx & 63;
    int h = (idx >> 6) & 7;
    int l = idx >> 9;
    float ang = ((float)l + htd[h]) * tang[h * 64 + d];
    float s, c;
    sincosf(ang, &s, &c);
    bf16* p = timef + ((size_t)l * NH + h) * TF;
    p[d]      = __float2bfloat16((c + s) * 0.125f);   // 1/sqrt(64)
    p[d + 64] = __float2bfloat16((c - s) * 0.125f);
}

// ---------------- bf16 MFMA GEMM: C = epi(A[M,K] @ Bt[N,K]^T) ----------------
// BM=BN=64, BK=32, 4 waves (2x2), wave tile 32x32. Double-buffered LDS:
// stage(next) issued BEFORE ds_read+MFMA(cur); one barrier per k-step
// (compiler inserts vmcnt(0) before s_barrier).
template<int EPI, typename OUTT>
__global__ __launch_bounds__(256) void gemm_mfma(const bf16* __restrict__ A,
                                                 const bf16* __restrict__ Bt,
                                                 const float* __restrict__ bias,
                                                 const float* __restrict__ res,
                                                 OUTT* __restrict__ C,
                                                 int M, int N, int K)
{
    __shared__ unsigned short As[2][64 * 32];
    __shared__ unsigned short Bs[2][64 * 32];

    int tid  = threadIdx.x;
    int lane = tid & 63, wave = tid >> 6;
    int wr = wave >> 1, wc = wave & 1;
    int bm = blockIdx.y * 64, bn = blockIdx.x * 64;
    int l15 = lane & 15, lk = lane >> 4;

    // staging: thread -> (row = tid>>2, k-chunk = (tid&3)*8); LDS dest tid*16B (linear)
    const bf16* ga = &A [(size_t)(bm + (tid >> 2)) * K + (tid & 3) * 8];
    const bf16* gb = &Bt[(size_t)(bn + (tid >> 2)) * K + (tid & 3) * 8];

    f32x4 acc[2][2] = {};
    int NT = K >> 5;

    gload16(ga, &As[0][tid * 8]);
    gload16(gb, &Bs[0][tid * 8]);
    __syncthreads();

    for (int t = 0; t < NT; ++t) {
        int cur = t & 1;
        if (t + 1 < NT) {
            gload16(ga + (t + 1) * 32, &As[cur ^ 1][tid * 8]);
            gload16(gb + (t + 1) * 32, &Bs[cur ^ 1][tid * 8]);
        }
        bf16x8 a[2], b[2];
        #pragma unroll
        for (int m = 0; m < 2; ++m)
            a[m] = *(const bf16x8*)&As[cur][(wr * 32 + m * 16 + l15) * 32 + lk * 8];
        #pragma unroll
        for (int n = 0; n < 2; ++n)
            b[n] = *(const bf16x8*)&Bs[cur][(wc * 32 + n * 16 + l15) * 32 + lk * 8];
        #pragma unroll
        for (int m = 0; m < 2; ++m)
            #pragma unroll
            for (int n = 0; n < 2; ++n)
                acc[m][n] = __builtin_amdgcn_mfma_f32_16x16x32_bf16(a[m], b[n], acc[m][n], 0, 0, 0);
        __syncthreads();
    }

    #pragma unroll
    for (int m = 0; m < 2; ++m) {
        #pragma unroll
        for (int n = 0; n < 2; ++n) {
            int gcol = bn + wc * 32 + n * 16 + l15;
            float bs = bias[gcol];
            #pragma unroll
            for (int r = 0; r < 4; ++r) {
                int grow = bm + wr * 32 + m * 16 + lk * 4 + r;
                float x = acc[m][n][r];
                float o;
                if constexpr (EPI == 0) {
                    o = (1.0f / (1.0f + expf(-(x - expf(bs))))) * (1.0f / 64.0f);
                } else if constexpr (EPI == 1) {
                    o = x + bs;
                } else if constexpr (EPI == 2) {
                    o = x + bs + res[(size_t)grow * N + gcol];
                } else if constexpr (EPI == 3) {
                    float t = x + bs;
                    float u = t + 0.044715f * t * t * t;
                    o = 0.5f * t * (1.0f + tanhf(0.7978845608028654f * u));
                } else {
                    o = x + bs + res[(size_t)grow * N + gcol];
                }
                stc(C, (size_t)grow * N + gcol, o);
            }
        }
    }
}

// ---------------- qsum[row][h] = mask[row] * sum_hd qraw[row, h*64+hd] ------
__global__ __launch_bounds__(256) void qsum_kernel(const bf16* __restrict__ qraw,
                                                   const float* __restrict__ mask,
                                                   float* __restrict__ qs)
{
    int row = blockIdx.x;
    int tid = threadIdx.x;
    const bf16* p = qraw + (size_t)row * DIM + tid * 2;   // head = tid/32
    float v = b2f(p[0]) + b2f(p[1]);
    #pragma unroll
    for (int off = 1; off < 32; off <<= 1) v += __shfl_xor(v, off);
    if ((tid & 31) == 0)
        qs[(size_t)row * NH + (tid >> 5)] = v * mask[row];
}

// ---- W^T partials: WT[bh][hd][d] = sum_t v[b,t,h,hd] * time[t,h,d] --------
__global__ __launch_bounds__(256) void wpart_kernel(const float* __restrict__ v,
                                                    const bf16* __restrict__ timef,
                                                    float* __restrict__ wpart)
{
    int bh = blockIdx.x;          // 0..15
    int kc = blockIdx.y;          // 0..KCH-1
    int b = bh >> 3, h = bh & 7;
    int hd = threadIdx.x & 63, dg = threadIdx.x >> 6;   // dg 0..3 -> d block

    float acc[32] = {};
    int t0 = kc * TCH;
    for (int t = t0; t < t0 + TCH; ++t) {
        float vv = v[((size_t)(b * LSEQ + t)) * DIM + h * HDIM + hd];
        const bf16* tp = timef + ((size_t)t * NH + h) * TF + dg * 32;
        bf16x8 tv[4];
        #pragma unroll
        for (int q = 0; q < 4; ++q) tv[q] = *(const bf16x8*)&tp[q * 8];
        #pragma unroll
        for (int q = 0; q < 4; ++q)
            #pragma unroll
            for (int j = 0; j < 8; ++j)
                acc[q * 8 + j] = fmaf((float)tv[q][j], vv, acc[q * 8 + j]);
    }
    // transposed store: [bh][hd][d]
    float* wp = wpart + ((size_t)(kc * 16 + bh)) * (TF * HDIM) + (size_t)hd * TF + dg * 32;
    #pragma unroll
    for (int q = 0; q < 8; ++q) {
        float4 o = {acc[q * 4], acc[q * 4 + 1], acc[q * 4 + 2], acc[q * 4 + 3]};
        ((float4*)wp)[q] = o;
    }
}

__global__ __launch_bounds__(256) void wred_kernel(const float* __restrict__ wpart,
                                                   bf16* __restrict__ WT)
{
    int i = blockIdx.x * 256 + threadIdx.x;   // < 16*64*128 = 131072 over [bh][hd][d]
    float s = 0.f;
    #pragma unroll
    for (int kc = 0; kc < KCH; ++kc)
        s += wpart[(size_t)kc * 131072 + i];
    WT[i] = __float2bfloat16(s);
}

// ---- comb[b,l,h,:] = qs[l,h] * (time[l,h,:] @ WT[bh]^T), MFMA --------------
// grid (bh=16, lt=8); 4 waves, each wave: 64 l-rows x 64 hd, K=128 (4 steps)
__global__ __launch_bounds__(256) void comb_mfma(const bf16* __restrict__ timef,
                                                 const bf16* __restrict__ WT,
                                                 const float* __restrict__ qs,
                                                 bf16* __restrict__ comb)
{
    int bh = blockIdx.x;
    int b = bh >> 3, h = bh & 7;
    int lane = threadIdx.x & 63, wave = threadIdx.x >> 6;
    int l15 = lane & 15, lk = lane >> 4;
    int lbase = blockIdx.y * 256 + wave * 64;

    const bf16* wt = WT + (size_t)bh * (HDIM * TF);

    f32x4 acc[4][4] = {};
    #pragma unroll
    for (int ks = 0; ks < 4; ++ks) {
        int kt = ks * 32;
        bf16x8 a[4], bf[4];
        #pragma unroll
        for (int m = 0; m < 4; ++m) {
            int l = lbase + m * 16 + l15;
            a[m] = *(const bf16x8*)&timef[((size_t)l * NH + h) * TF + kt + lk * 8];
        }
        #pragma unroll
        for (int n = 0; n < 4; ++n)
            bf[n] = *(const bf16x8*)&wt[(size_t)(n * 16 + l15) * TF + kt + lk * 8];
        #pragma unroll
        for (int m = 0; m < 4; ++m)
            #pragma unroll
            for (int n = 0; n < 4; ++n)
                acc[m][n] = __builtin_amdgcn_mfma_f32_16x16x32_bf16(a[m], bf[n], acc[m][n], 0, 0, 0);
    }

    #pragma unroll
    for (int m = 0; m < 4; ++m) {
        #pragma unroll
        for (int r = 0; r < 4; ++r) {
            int l = lbase + m * 16 + lk * 4 + r;
            float q = qs[(size_t)(b * LSEQ + l) * NH + h];
            #pragma unroll
            for (int n = 0; n < 4; ++n) {
                int hd = n * 16 + l15;
                comb[(size_t)(b * LSEQ + l) * DIM + h * HDIM + hd] =
                    __float2bfloat16(q * acc[m][n][r]);
            }
        }
    }
}

// ---------------- LayerNorm over last dim (512) ----------------
template<int WB>
__global__ __launch_bounds__(256) void ln_kernel(const float* __restrict__ X,
                                                 const float* __restrict__ g,
                                                 const float* __restrict__ bta,
                                                 float* __restrict__ outf,
                                                 bf16* __restrict__ outb)
{
    int row = blockIdx.x;
    const float* x = X + (size_t)row * DIM;
    float v0 = x[threadIdx.x], v1 = x[threadIdx.x + 256];
    float s = v0 + v1, s2 = v0 * v0 + v1 * v1;
    #pragma unroll
    for (int off = 1; off < 64; off <<= 1) {
        s  += __shfl_xor(s,  off);
        s2 += __shfl_xor(s2, off);
    }
    __shared__ float sh[2][4];
    int wave = threadIdx.x >> 6, lane = threadIdx.x & 63;
    if (lane == 0) { sh[0][wave] = s; sh[1][wave] = s2; }
    __syncthreads();
    s  = sh[0][0] + sh[0][1] + sh[0][2] + sh[0][3];
    s2 = sh[1][0] + sh[1][1] + sh[1][2] + sh[1][3];
    float mu  = s * (1.0f / DIM);
    float var = s2 * (1.0f / DIM) - mu * mu;
    float inv = rsqrtf(var + 1e-5f);
    int c0 = threadIdx.x, c1 = threadIdx.x + 256;
    float o0 = (v0 - mu) * inv * g[c0] + bta[c0];
    float o1 = (v1 - mu) * inv * g[c1] + bta[c1];
    outf[(size_t)row * DIM + c0] = o0;
    outf[(size_t)row * DIM + c1] = o1;
    if constexpr (WB) {
        outb[(size_t)row * DIM + c0] = __float2bfloat16(o0);
        outb[(size_t)row * DIM + c1] = __float2bfloat16(o1);
    }
}

extern "C" void kernel_launch(void* const* d_in, const int* in_sizes, int n_in,
                              void* d_out, int out_size, void* d_ws, size_t ws_size,
                              hipStream_t stream)
{
    const float* tensor = (const float*)d_in[0];
    const float* mask   = (const float*)d_in[1];
    const float* tang   = (const float*)d_in[2];
    const float* htd    = (const float*)d_in[3];
    const float* Qw     = (const float*)d_in[4];
    const float* qb     = (const float*)d_in[5];
    // d_in[6], d_in[7] (Kw, Kb) dead code
    const float* Vw     = (const float*)d_in[8];
    const float* Vb     = (const float*)d_in[9];
    const float* Ow     = (const float*)d_in[10];
    const float* Ob     = (const float*)d_in[11];
    const float* g1     = (const float*)d_in[12];
    const float* b1     = (const float*)d_in[13];
    const float* Win    = (const float*)d_in[14];
    const float* bin    = (const float*)d_in[15];
    const float* Wout   = (const float*)d_in[16];
    const float* bout   = (const float*)d_in[17];
    const float* g2     = (const float*)d_in[18];
    const float* b2     = (const float*)d_in[19];
    float* out = (float*)d_out;

    float* ws = (float*)d_ws;
    // f32-unit offsets (lifetimes as round 5; Wm region now WT bf16 + qs f32):
    //   vbuf    [0,        2097152)  v: s3->s4        preLN1: s6->s7
    //   actb    [0,        3145728)  bf16 FFN act:    s8->s9
    //   tensorb [2097152,  3145728)  s0->s3; combb reuse: s5->s6
    //   timefb  [3145728,  4194304)  s1->s5
    //   qrawb   [4194304,  5242880)  s2->s2.5
    //   wpart   [5242880,  7340032)  s4->s4.5; buf5 reuse: s9->s10
    //   interb  [7340032,  8388608)  s7->s8
    //   WTb     [8388608,  8454144)  bf16 [16][64][128]: s4.5->s5
    //   qs      [8454144,  8486912)  f32 [4096][8]:      s2.5->s5
    //   QwT     [8519680,  8650752)  s0->s2
    //   VwT     [8650752,  8781824)  s0->s3
    //   OwT     [8781824,  8912896)  s0->s6
    //   WinT    [8912896,  9306112)  s0->s8
    //   WoutT   [9306112,  9699328)  s0->s9
    //   inter   [9699328, 11796480)  s7->s9
    float* vbuf   = ws + 0;
    bf16*  actb   = (bf16*)(ws + 0);
    bf16*  tensorb= (bf16*)(ws + 2097152);
    bf16*  combb  = tensorb;
    bf16*  timefb = (bf16*)(ws + 3145728);
    bf16*  qrawb  = (bf16*)(ws + 4194304);
    float* wpart  = ws + 5242880;
    float* buf5   = ws + 5242880;
    bf16*  interb = (bf16*)(ws + 7340032);
    bf16*  WTb    = (bf16*)(ws + 8388608);
    float* qs     = ws + 8454144;
    bf16*  QwT    = (bf16*)(ws + 8519680);
    bf16*  VwT    = (bf16*)(ws + 8650752);
    bf16*  OwT    = (bf16*)(ws + 8781824);
    bf16*  WinT   = (bf16*)(ws + 8912896);
    bf16*  WoutT  = (bf16*)(ws + 9306112);
    float* inter  = ws + 9699328;

    // 0. precompute
    cvt_kernel<<<2048, 256, 0, stream>>>(tensor, tensorb);
    transpose_kernel<<<dim3(16, 16), 256, 0, stream>>>(Qw,  QwT,  DIM, DIM);
    transpose_kernel<<<dim3(16, 16), 256, 0, stream>>>(Vw,  VwT,  DIM, DIM);
    transpose_kernel<<<dim3(16, 16), 256, 0, stream>>>(Ow,  OwT,  DIM, DIM);
    transpose_kernel<<<dim3(48, 16), 256, 0, stream>>>(Win, WinT, DIM, LIND);
    transpose_kernel<<<dim3(16, 48), 256, 0, stream>>>(Wout, WoutT, LIND, DIM);
    time_kernel<<<4096, 256, 0, stream>>>(tang, htd, timefb);
    // 2. Q gate -> bf16, then row-sums
    gemm_mfma<0, bf16><<<dim3(8, 64), 256, 0, stream>>>(tensorb, QwT, qb, nullptr, qrawb, ROWS, DIM, DIM);
    qsum_kernel<<<ROWS, 256, 0, stream>>>(qrawb, mask, qs);
    // 3. V projection -> f32
    gemm_mfma<1, float><<<dim3(8, 64), 256, 0, stream>>>(tensorb, VwT, Vb, nullptr, vbuf, ROWS, DIM, DIM);
    // 4. WT = (time^T @ v)^T per (b,h), split-K then reduce->bf16
    wpart_kernel<<<dim3(16, KCH), 256, 0, stream>>>(vbuf, timefb, wpart);
    wred_kernel<<<512, 256, 0, stream>>>(wpart, WTb);
    // 5. comb via MFMA
    comb_mfma<<<dim3(16, 8), 256, 0, stream>>>(timefb, WTb, qs, combb);
    // 6. attn_out + residual(tensor) -> preLN1
    gemm_mfma<2, float><<<dim3(8, 64), 256, 0, stream>>>(combb, OwT, Ob, tensor, vbuf, ROWS, DIM, DIM);
    // 7. LN1 -> inter f32 + interb bf16
    ln_kernel<1><<<ROWS, 256, 0, stream>>>(vbuf, g1, b1, inter, interb);
    // 8. FFN in + gelu -> bf16
    gemm_mfma<3, bf16><<<dim3(24, 64), 256, 0, stream>>>(interb, WinT, bin, nullptr, actb, ROWS, LIND, DIM);
    // 9. FFN out + residual(inter)
    gemm_mfma<4, float><<<dim3(8, 64), 256, 0, stream>>>(actb, WoutT, bout, inter, buf5, ROWS, DIM, LIND);
    // 10. LN2 -> f32 output
    ln_kernel<0><<<ROWS, 256, 0, stream>>>(buf5, g2, b2, out, nullptr);
}

// Round 7
// 151.149 us; speedup vs baseline: 3.6193x; 1.1577x over previous
//
#include <hip/hip_runtime.h>
#include <hip/hip_bf16.h>

typedef __hip_bfloat16 bf16;
typedef __attribute__((ext_vector_type(8))) __bf16 bf16x8;
typedef __attribute__((ext_vector_type(4))) float f32x4;

#define DIM   512
#define NH    8
#define HDIM  64
#define LIND  1536
#define LSEQ  2048
#define ROWS  4096        // B*L
#define TF    128         // time features
#define KCH   32          // wpart split-K chunks
#define TCH   64          // t per chunk

__device__ __forceinline__ float b2f(bf16 v){ return __bfloat162float(v); }
__device__ __forceinline__ void stc(float* C, size_t i, float v){ C[i] = v; }
__device__ __forceinline__ void stc(bf16*  C, size_t i, float v){ C[i] = __float2bfloat16(v); }

typedef const __attribute__((address_space(1))) unsigned int* gp1_t;
typedef __attribute__((address_space(3))) unsigned int* lp3_t;
__device__ __forceinline__ void gload16(const bf16* g, unsigned short* l) {
    __builtin_amdgcn_global_load_lds((gp1_t)(const void*)g, (lp3_t)(void*)l, 16, 0, 0);
}

// ---------------- f32 -> bf16 convert (4 elems/thread) ----------------
__global__ __launch_bounds__(256) void cvt_kernel(const float* __restrict__ in,
                                                  bf16* __restrict__ out)
{
    int i = blockIdx.x * 256 + threadIdx.x;
    float4 v = ((const float4*)in)[i];
    bf16 t[4];
    t[0] = __float2bfloat16(v.x); t[1] = __float2bfloat16(v.y);
    t[2] = __float2bfloat16(v.z); t[3] = __float2bfloat16(v.w);
    *(uint2*)&out[(size_t)i * 4] = *(uint2*)t;
}

// ------- fused weight transposes: all 5 weights, f32 [R][C] -> bf16 [C][R] ---
__global__ __launch_bounds__(256) void transpose_all(const float* __restrict__ Qw,
                                                     const float* __restrict__ Vw,
                                                     const float* __restrict__ Ow,
                                                     const float* __restrict__ Win,
                                                     const float* __restrict__ Wout,
                                                     bf16* __restrict__ QwT,
                                                     bf16* __restrict__ VwT,
                                                     bf16* __restrict__ OwT,
                                                     bf16* __restrict__ WinT,
                                                     bf16* __restrict__ WoutT)
{
    int id = blockIdx.x;
    const float* in; bf16* out; int R, C, tx, ty;
    if (id < 256)        { in = Qw;   out = QwT;   R = 512;  C = 512;  tx = id & 15; ty = id >> 4; }
    else if (id < 512)   { id -= 256;  in = Vw;   out = VwT;   R = 512;  C = 512;  tx = id & 15; ty = id >> 4; }
    else if (id < 768)   { id -= 512;  in = Ow;   out = OwT;   R = 512;  C = 512;  tx = id & 15; ty = id >> 4; }
    else if (id < 1536)  { id -= 768;  in = Win;  out = WinT;  R = 512;  C = 1536; tx = id % 48; ty = id / 48; }
    else                 { id -= 1536; in = Wout; out = WoutT; R = 1536; C = 512;  tx = id & 15; ty = id >> 4; }

    __shared__ float t[32][33];
    int bx = tx * 32, by = ty * 32;
    int x = threadIdx.x & 31, y = threadIdx.x >> 5;   // y: 0..7
    #pragma unroll
    for (int r = 0; r < 32; r += 8)
        t[y + r][x] = in[(size_t)(by + y + r) * C + bx + x];
    __syncthreads();
    #pragma unroll
    for (int r = 0; r < 32; r += 8)
        out[(size_t)(bx + y + r) * R + by + x] = __float2bfloat16(t[x][y + r]);
}

// ---------------- time features (bf16): time[l][h][0:128] ----------------
__global__ __launch_bounds__(256) void time_kernel(const float* __restrict__ tang,
                                                   const float* __restrict__ htd,
                                                   bf16* __restrict__ timef)
{
    int idx = blockIdx.x * 256 + threadIdx.x;     // < LSEQ*NH*64 = 1048576
    int d = idx & 63;
    int h = (idx >> 6) & 7;
    int l = idx >> 9;
    float ang = ((float)l + htd[h]) * tang[h * 64 + d];
    float s, c;
    sincosf(ang, &s, &c);
    bf16* p = timef + ((size_t)l * NH + h) * TF;
    p[d]      = __float2bfloat16((c + s) * 0.125f);   // 1/sqrt(64)
    p[d + 64] = __float2bfloat16((c - s) * 0.125f);
}

// ---------------- bf16 MFMA GEMM: C = epi(A[M,K] @ Bt[N,K]^T) ----------------
// BM=BN=64, BK=32, 4 waves (2x2), wave tile 32x32, double-buffered LDS.
template<int EPI, typename OUTT>
__global__ __launch_bounds__(256) void gemm_mfma(const bf16* __restrict__ A,
                                                 const bf16* __restrict__ Bt,
                                                 const float* __restrict__ bias,
                                                 const float* __restrict__ res,
                                                 OUTT* __restrict__ C,
                                                 int M, int N, int K)
{
    __shared__ unsigned short As[2][64 * 32];
    __shared__ unsigned short Bs[2][64 * 32];

    int tid  = threadIdx.x;
    int lane = tid & 63, wave = tid >> 6;
    int wr = wave >> 1, wc = wave & 1;
    int bm = blockIdx.y * 64, bn = blockIdx.x * 64;
    int l15 = lane & 15, lk = lane >> 4;

    const bf16* ga = &A [(size_t)(bm + (tid >> 2)) * K + (tid & 3) * 8];
    const bf16* gb = &Bt[(size_t)(bn + (tid >> 2)) * K + (tid & 3) * 8];

    f32x4 acc[2][2] = {};
    int NT = K >> 5;

    gload16(ga, &As[0][tid * 8]);
    gload16(gb, &Bs[0][tid * 8]);
    __syncthreads();

    for (int t = 0; t < NT; ++t) {
        int cur = t & 1;
        if (t + 1 < NT) {
            gload16(ga + (t + 1) * 32, &As[cur ^ 1][tid * 8]);
            gload16(gb + (t + 1) * 32, &Bs[cur ^ 1][tid * 8]);
        }
        bf16x8 a[2], b[2];
        #pragma unroll
        for (int m = 0; m < 2; ++m)
            a[m] = *(const bf16x8*)&As[cur][(wr * 32 + m * 16 + l15) * 32 + lk * 8];
        #pragma unroll
        for (int n = 0; n < 2; ++n)
            b[n] = *(const bf16x8*)&Bs[cur][(wc * 32 + n * 16 + l15) * 32 + lk * 8];
        #pragma unroll
        for (int m = 0; m < 2; ++m)
            #pragma unroll
            for (int n = 0; n < 2; ++n)
                acc[m][n] = __builtin_amdgcn_mfma_f32_16x16x32_bf16(a[m], b[n], acc[m][n], 0, 0, 0);
        __syncthreads();
    }

    #pragma unroll
    for (int m = 0; m < 2; ++m) {
        #pragma unroll
        for (int n = 0; n < 2; ++n) {
            int gcol = bn + wc * 32 + n * 16 + l15;
            float bs = bias[gcol];
            #pragma unroll
            for (int r = 0; r < 4; ++r) {
                int grow = bm + wr * 32 + m * 16 + lk * 4 + r;
                float x = acc[m][n][r];
                float o;
                if constexpr (EPI == 0) {
                    o = (1.0f / (1.0f + expf(-(x - expf(bs))))) * (1.0f / 64.0f);
                } else if constexpr (EPI == 1) {
                    o = x + bs;
                } else if constexpr (EPI == 2) {
                    o = x + bs + res[(size_t)grow * N + gcol];
                } else if constexpr (EPI == 3) {
                    float t = x + bs;
                    float u = t + 0.044715f * t * t * t;
                    o = 0.5f * t * (1.0f + tanhf(0.7978845608028654f * u));
                } else {
                    o = x + bs + res[(size_t)grow * N + gcol];
                }
                stc(C, (size_t)grow * N + gcol, o);
            }
        }
    }
}

// ---------------- qsum[row][h] = mask[row] * sum_hd qraw[row, h*64+hd] ------
__global__ __launch_bounds__(256) void qsum_kernel(const bf16* __restrict__ qraw,
                                                   const float* __restrict__ mask,
                                                   float* __restrict__ qs)
{
    int row = blockIdx.x;
    int tid = threadIdx.x;
    const bf16* p = qraw + (size_t)row * DIM + tid * 2;   // head = tid/32
    float v = b2f(p[0]) + b2f(p[1]);
    #pragma unroll
    for (int off = 1; off < 32; off <<= 1) v += __shfl_xor(v, off);
    if ((tid & 31) == 0)
        qs[(size_t)row * NH + (tid >> 5)] = v * mask[row];
}

// ---- W^T partials: WT[bh][hd][d] = sum_t v[b,t,h,hd] * time[t,h,d] --------
__global__ __launch_bounds__(256) void wpart_kernel(const float* __restrict__ v,
                                                    const bf16* __restrict__ timef,
                                                    float* __restrict__ wpart)
{
    int bh = blockIdx.x;          // 0..15
    int kc = blockIdx.y;          // 0..KCH-1
    int b = bh >> 3, h = bh & 7;
    int hd = threadIdx.x & 63, dg = threadIdx.x >> 6;   // dg 0..3 -> d block

    float acc[32] = {};
    int t0 = kc * TCH;
    #pragma unroll 4
    for (int t = t0; t < t0 + TCH; ++t) {
        float vv = v[((size_t)(b * LSEQ + t)) * DIM + h * HDIM + hd];
        const bf16* tp = timef + ((size_t)t * NH + h) * TF + dg * 32;
        bf16x8 tv[4];
        #pragma unroll
        for (int q = 0; q < 4; ++q) tv[q] = *(const bf16x8*)&tp[q * 8];
        #pragma unroll
        for (int q = 0; q < 4; ++q)
            #pragma unroll
            for (int j = 0; j < 8; ++j)
                acc[q * 8 + j] = fmaf((float)tv[q][j], vv, acc[q * 8 + j]);
    }
    // transposed store: [bh][hd][d]
    float* wp = wpart + ((size_t)(kc * 16 + bh)) * (TF * HDIM) + (size_t)hd * TF + dg * 32;
    #pragma unroll
    for (int q = 0; q < 8; ++q) {
        float4 o = {acc[q * 4], acc[q * 4 + 1], acc[q * 4 + 2], acc[q * 4 + 3]};
        ((float4*)wp)[q] = o;
    }
}

__global__ __launch_bounds__(256) void wred_kernel(const float* __restrict__ wpart,
                                                   bf16* __restrict__ WT)
{
    int i = blockIdx.x * 256 + threadIdx.x;   // < 16*64*128 = 131072 over [bh][hd][d]
    float s = 0.f;
    #pragma unroll
    for (int kc = 0; kc < KCH; ++kc)
        s += wpart[(size_t)kc * 131072 + i];
    WT[i] = __float2bfloat16(s);
}

// ---- comb[b,l,h,:] = qs[l,h] * (time[l,h,:] @ WT[bh]^T), MFMA --------------
__global__ __launch_bounds__(256) void comb_mfma(const bf16* __restrict__ timef,
                                                 const bf16* __restrict__ WT,
                                                 const float* __restrict__ qs,
                                                 bf16* __restrict__ comb)
{
    int bh = blockIdx.x;
    int b = bh >> 3, h = bh & 7;
    int lane = threadIdx.x & 63, wave = threadIdx.x >> 6;
    int l15 = lane & 15, lk = lane >> 4;
    int lbase = blockIdx.y * 256 + wave * 64;

    const bf16* wt = WT + (size_t)bh * (HDIM * TF);

    f32x4 acc[4][4] = {};
    #pragma unroll
    for (int ks = 0; ks < 4; ++ks) {
        int kt = ks * 32;
        bf16x8 a[4], bf[4];
        #pragma unroll
        for (int m = 0; m < 4; ++m) {
            int l = lbase + m * 16 + l15;
            a[m] = *(const bf16x8*)&timef[((size_t)l * NH + h) * TF + kt + lk * 8];
        }
        #pragma unroll
        for (int n = 0; n < 4; ++n)
            bf[n] = *(const bf16x8*)&wt[(size_t)(n * 16 + l15) * TF + kt + lk * 8];
        #pragma unroll
        for (int m = 0; m < 4; ++m)
            #pragma unroll
            for (int n = 0; n < 4; ++n)
                acc[m][n] = __builtin_amdgcn_mfma_f32_16x16x32_bf16(a[m], bf[n], acc[m][n], 0, 0, 0);
    }

    #pragma unroll
    for (int m = 0; m < 4; ++m) {
        #pragma unroll
        for (int r = 0; r < 4; ++r) {
            int l = lbase + m * 16 + lk * 4 + r;
            float q = qs[(size_t)(b * LSEQ + l) * NH + h];
            #pragma unroll
            for (int n = 0; n < 4; ++n) {
                int hd = n * 16 + l15;
                comb[(size_t)(b * LSEQ + l) * DIM + h * HDIM + hd] =
                    __float2bfloat16(q * acc[m][n][r]);
            }
        }
    }
}

// ---------------- LayerNorm over last dim (512) ----------------
template<int WB>
__global__ __launch_bounds__(256) void ln_kernel(const float* __restrict__ X,
                                                 const float* __restrict__ g,
                                                 const float* __restrict__ bta,
                                                 float* __restrict__ outf,
                                                 bf16* __restrict__ outb)
{
    int row = blockIdx.x;
    const float* x = X + (size_t)row * DIM;
    float v0 = x[threadIdx.x], v1 = x[threadIdx.x + 256];
    float s = v0 + v1, s2 = v0 * v0 + v1 * v1;
    #pragma unroll
    for (int off = 1; off < 64; off <<= 1) {
        s  += __shfl_xor(s,  off);
        s2 += __shfl_xor(s2, off);
    }
    __shared__ float sh[2][4];
    int wave = threadIdx.x >> 6, lane = threadIdx.x & 63;
    if (lane == 0) { sh[0][wave] = s; sh[1][wave] = s2; }
    __syncthreads();
    s  = sh[0][0] + sh[0][1] + sh[0][2] + sh[0][3];
    s2 = sh[1][0] + sh[1][1] + sh[1][2] + sh[1][3];
    float mu  = s * (1.0f / DIM);
    float var = s2 * (1.0f / DIM) - mu * mu;
    float inv = rsqrtf(var + 1e-5f);
    int c0 = threadIdx.x, c1 = threadIdx.x + 256;
    float o0 = (v0 - mu) * inv * g[c0] + bta[c0];
    float o1 = (v1 - mu) * inv * g[c1] + bta[c1];
    outf[(size_t)row * DIM + c0] = o0;
    outf[(size_t)row * DIM + c1] = o1;
    if constexpr (WB) {
        outb[(size_t)row * DIM + c0] = __float2bfloat16(o0);
        outb[(size_t)row * DIM + c1] = __float2bfloat16(o1);
    }
}

extern "C" void kernel_launch(void* const* d_in, const int* in_sizes, int n_in,
                              void* d_out, int out_size, void* d_ws, size_t ws_size,
                              hipStream_t stream)
{
    const float* tensor = (const float*)d_in[0];
    const float* mask   = (const float*)d_in[1];
    const float* tang   = (const float*)d_in[2];
    const float* htd    = (const float*)d_in[3];
    const float* Qw     = (const float*)d_in[4];
    const float* qb     = (const float*)d_in[5];
    // d_in[6], d_in[7] (Kw, Kb) dead code
    const float* Vw     = (const float*)d_in[8];
    const float* Vb     = (const float*)d_in[9];
    const float* Ow     = (const float*)d_in[10];
    const float* Ob     = (const float*)d_in[11];
    const float* g1     = (const float*)d_in[12];
    const float* b1     = (const float*)d_in[13];
    const float* Win    = (const float*)d_in[14];
    const float* bin    = (const float*)d_in[15];
    const float* Wout   = (const float*)d_in[16];
    const float* bout   = (const float*)d_in[17];
    const float* g2     = (const float*)d_in[18];
    const float* b2     = (const float*)d_in[19];
    float* out = (float*)d_out;

    float* ws = (float*)d_ws;
    // f32-unit offsets. Lifetimes (written -> last read):
    //   vbuf    [0,        2097152)  v: s3->s4;   preLN1: s6->s7
    //   actb    [0,        3145728)  bf16 FFN act: s8->s9
    //   tensorb [2097152,  3145728)  s0->s3; combb reuse: s5->s6
    //   timefb  [3145728,  4194304)  s1->s5
    //   qrawb   [4194304,  5242880)  s2->s2.5; interb reuse: s7->s8
    //   wpart   [5242880,  9437184)  s4->s4.5  (32 chunks x 131072)
    //   buf5    [5242880,  7340032)  preLN2: s9->s10
    //   inter   [7340032,  9437184)  f32: s7->s9
    //   WTb     [9437184,  9502720)  bf16: s4.5->s5
    //   qs      [9502720,  9535488)  f32:  s2.5->s5
    //   QwT     [9535488,  9666560)  s0->s2
    //   VwT     [9666560,  9797632)  s0->s3
    //   OwT     [9797632,  9928704)  s0->s6
    //   WinT    [9928704, 10321920)  s0->s8
    //   WoutT   [10321920,10715136)  s0->s9
    // peak = 10715136 f32 = 42.9 MB (< 47.2 MB proven round 5)
    float* vbuf   = ws + 0;
    bf16*  actb   = (bf16*)(ws + 0);
    bf16*  tensorb= (bf16*)(ws + 2097152);
    bf16*  combb  = tensorb;
    bf16*  timefb = (bf16*)(ws + 3145728);
    bf16*  qrawb  = (bf16*)(ws + 4194304);
    bf16*  interb = (bf16*)(ws + 4194304);
    float* wpart  = ws + 5242880;
    float* buf5   = ws + 5242880;
    float* inter  = ws + 7340032;
    bf16*  WTb    = (bf16*)(ws + 9437184);
    float* qs     = ws + 9502720;
    bf16*  QwT    = (bf16*)(ws + 9535488);
    bf16*  VwT    = (bf16*)(ws + 9666560);
    bf16*  OwT    = (bf16*)(ws + 9797632);
    bf16*  WinT   = (bf16*)(ws + 9928704);
    bf16*  WoutT  = (bf16*)(ws + 10321920);

    // 0. precompute
    cvt_kernel<<<2048, 256, 0, stream>>>(tensor, tensorb);
    transpose_all<<<2304, 256, 0, stream>>>(Qw, Vw, Ow, Win, Wout, QwT, VwT, OwT, WinT, WoutT);
    time_kernel<<<4096, 256, 0, stream>>>(tang, htd, timefb);
    // 2. Q gate -> bf16, then row-sums
    gemm_mfma<0, bf16><<<dim3(8, 64), 256, 0, stream>>>(tensorb, QwT, qb, nullptr, qrawb, ROWS, DIM, DIM);
    qsum_kernel<<<ROWS, 256, 0, stream>>>(qrawb, mask, qs);
    // 3. V projection -> f32
    gemm_mfma<1, float><<<dim3(8, 64), 256, 0, stream>>>(tensorb, VwT, Vb, nullptr, vbuf, ROWS, DIM, DIM);
    // 4. WT = (time^T @ v)^T per (b,h), split-K 32 then reduce->bf16
    wpart_kernel<<<dim3(16, KCH), 256, 0, stream>>>(vbuf, timefb, wpart);
    wred_kernel<<<512, 256, 0, stream>>>(wpart, WTb);
    // 5. comb via MFMA
    comb_mfma<<<dim3(16, 8), 256, 0, stream>>>(timefb, WTb, qs, combb);
    // 6. attn_out + residual(tensor) -> preLN1
    gemm_mfma<2, float><<<dim3(8, 64), 256, 0, stream>>>(combb, OwT, Ob, tensor, vbuf, ROWS, DIM, DIM);
    // 7. LN1 -> inter f32 + interb bf16
    ln_kernel<1><<<ROWS, 256, 0, stream>>>(vbuf, g1, b1, inter, interb);
    // 8. FFN in + gelu -> bf16
    gemm_mfma<3, bf16><<<dim3(24, 64), 256, 0, stream>>>(interb, WinT, bin, nullptr, actb, ROWS, LIND, DIM);
    // 9. FFN out + residual(inter)
    gemm_mfma<4, float><<<dim3(8, 64), 256, 0, stream>>>(actb, WoutT, bout, inter, buf5, ROWS, DIM, LIND);
    // 10. LN2 -> f32 output
    ln_kernel<0><<<ROWS, 256, 0, stream>>>(buf5, g2, b2, out, nullptr);
}

// Round 8
// 132.011 us; speedup vs baseline: 4.1440x; 1.1450x over previous
//
#include <hip/hip_runtime.h>
#include <hip/hip_bf16.h>

typedef __hip_bfloat16 bf16;
typedef __attribute__((ext_vector_type(8))) __bf16 bf16x8;
typedef __attribute__((ext_vector_type(4))) float f32x4;

#define DIM   512
#define NH    8
#define HDIM  64
#define LIND  1536
#define LSEQ  2048
#define ROWS  4096        // B*L
#define TF    128         // time features
#define KCH   32          // wpart split-K chunks
#define TCH   64          // t per chunk

__device__ __forceinline__ float b2f(bf16 v){ return __bfloat162float(v); }
__device__ __forceinline__ void stc(float* C, size_t i, float v){ C[i] = v; }
__device__ __forceinline__ void stc(bf16*  C, size_t i, float v){ C[i] = __float2bfloat16(v); }

typedef const __attribute__((address_space(1))) unsigned int* gp1_t;
typedef __attribute__((address_space(3))) unsigned int* lp3_t;
__device__ __forceinline__ void gload16(const bf16* g, unsigned short* l) {
    __builtin_amdgcn_global_load_lds((gp1_t)(const void*)g, (lp3_t)(void*)l, 16, 0, 0);
}

// ---------- prep: tensor->bf16 (blocks 0..2047), time features (2048..6143) ----------
__global__ __launch_bounds__(256) void prep_kernel(const float* __restrict__ tensor,
                                                   const float* __restrict__ tang,
                                                   const float* __restrict__ htd,
                                                   bf16* __restrict__ tensorb,
                                                   bf16* __restrict__ timef)
{
    int id = blockIdx.x;
    if (id < 2048) {
        int i = id * 256 + threadIdx.x;
        float4 v = ((const float4*)tensor)[i];
        bf16 t[4];
        t[0] = __float2bfloat16(v.x); t[1] = __float2bfloat16(v.y);
        t[2] = __float2bfloat16(v.z); t[3] = __float2bfloat16(v.w);
        *(uint2*)&tensorb[(size_t)i * 4] = *(uint2*)t;
    } else {
        int idx = (id - 2048) * 256 + threadIdx.x;   // < 1048576
        int d = idx & 63;
        int h = (idx >> 6) & 7;
        int l = idx >> 9;
        float ang = ((float)l + htd[h]) * tang[h * 64 + d];
        float s, c;
        sincosf(ang, &s, &c);
        bf16* p = timef + ((size_t)l * NH + h) * TF;
        p[d]      = __float2bfloat16((c + s) * 0.125f);
        p[d + 64] = __float2bfloat16((c - s) * 0.125f);
    }
}

// ------- fused weight transposes: f32 [R][C] -> bf16 [C][R] (5 weights) ---
__global__ __launch_bounds__(256) void transpose_all(const float* __restrict__ Qw,
                                                     const float* __restrict__ Vw,
                                                     const float* __restrict__ Ow,
                                                     const float* __restrict__ Win,
                                                     const float* __restrict__ Wout,
                                                     bf16* __restrict__ QwT,
                                                     bf16* __restrict__ VwT,
                                                     bf16* __restrict__ OwT,
                                                     bf16* __restrict__ WinT,
                                                     bf16* __restrict__ WoutT)
{
    int id = blockIdx.x;
    const float* in; bf16* out; int R, C, tx, ty;
    if (id < 256)        { in = Qw;   out = QwT;   R = 512;  C = 512;  tx = id & 15; ty = id >> 4; }
    else if (id < 512)   { id -= 256;  in = Vw;   out = VwT;   R = 512;  C = 512;  tx = id & 15; ty = id >> 4; }
    else if (id < 768)   { id -= 512;  in = Ow;   out = OwT;   R = 512;  C = 512;  tx = id & 15; ty = id >> 4; }
    else if (id < 1536)  { id -= 768;  in = Win;  out = WinT;  R = 512;  C = 1536; tx = id % 48; ty = id / 48; }
    else                 { id -= 1536; in = Wout; out = WoutT; R = 1536; C = 512;  tx = id & 15; ty = id >> 4; }

    __shared__ float t[32][33];
    int bx = tx * 32, by = ty * 32;
    int x = threadIdx.x & 31, y = threadIdx.x >> 5;
    #pragma unroll
    for (int r = 0; r < 32; r += 8)
        t[y + r][x] = in[(size_t)(by + y + r) * C + bx + x];
    __syncthreads();
    #pragma unroll
    for (int r = 0; r < 32; r += 8)
        out[(size_t)(bx + y + r) * R + by + x] = __float2bfloat16(t[x][y + r]);
}

// ===== BK=64 double-buffered MFMA GEMM core pieces (XOR-swizzled LDS) =====
// LDS tile [64 rows][64 k] ushort; staging slot e: row=e>>3, granule g=e&7
// holds GLOBAL granule g^(row&7); reads XOR the same way. 2-way bank alias only.

// ---------------- generic GEMM: C = epi(A[M,K] @ Bt[N,K]^T) ----------------
// EPI: 2 = x+b+res (O)   3 = gelu(x+b) (FFN1)   4 = x+b+res (FFN2)
template<int EPI, typename OUTT>
__global__ __launch_bounds__(256) void gemm64(const bf16* __restrict__ A,
                                              const bf16* __restrict__ Bt,
                                              const float* __restrict__ bias,
                                              const float* __restrict__ res,
                                              OUTT* __restrict__ C,
                                              int M, int N, int K)
{
    __shared__ unsigned short As[2][64 * 64];
    __shared__ unsigned short Bs[2][64 * 64];

    int tid  = threadIdx.x;
    int lane = tid & 63, wave = tid >> 6;
    int wr = wave >> 1, wc = wave & 1;
    int bm = blockIdx.y * 64, bn = blockIdx.x * 64;
    int l15 = lane & 15, lk = lane >> 4;

    const bf16* gA[2]; const bf16* gB[2];
    #pragma unroll
    for (int it = 0; it < 2; ++it) {
        int e = it * 256 + tid, row = e >> 3, g = e & 7;
        int kc = (g ^ (row & 7)) * 8;
        gA[it] = &A [(size_t)(bm + row) * K + kc];
        gB[it] = &Bt[(size_t)(bn + row) * K + kc];
    }

    f32x4 acc[2][2] = {};
    int NT = K >> 6;

    #pragma unroll
    for (int it = 0; it < 2; ++it) {
        gload16(gA[it], &As[0][(it * 256 + tid) * 8]);
        gload16(gB[it], &Bs[0][(it * 256 + tid) * 8]);
    }
    __syncthreads();

    for (int t = 0; t < NT; ++t) {
        int cur = t & 1;
        if (t + 1 < NT) {
            #pragma unroll
            for (int it = 0; it < 2; ++it) {
                gload16(gA[it] + (t + 1) * 64, &As[cur ^ 1][(it * 256 + tid) * 8]);
                gload16(gB[it] + (t + 1) * 64, &Bs[cur ^ 1][(it * 256 + tid) * 8]);
            }
        }
        #pragma unroll
        for (int s = 0; s < 2; ++s) {
            bf16x8 a[2], b[2];
            #pragma unroll
            for (int m = 0; m < 2; ++m) {
                int row = wr * 32 + m * 16 + l15;
                a[m] = *(const bf16x8*)&As[cur][row * 64 + ((s * 4 + lk) ^ (l15 & 7)) * 8];
            }
            #pragma unroll
            for (int n = 0; n < 2; ++n) {
                int row = wc * 32 + n * 16 + l15;
                b[n] = *(const bf16x8*)&Bs[cur][row * 64 + ((s * 4 + lk) ^ (l15 & 7)) * 8];
            }
            #pragma unroll
            for (int m = 0; m < 2; ++m)
                #pragma unroll
                for (int n = 0; n < 2; ++n)
                    acc[m][n] = __builtin_amdgcn_mfma_f32_16x16x32_bf16(a[m], b[n], acc[m][n], 0, 0, 0);
        }
        __syncthreads();
    }

    #pragma unroll
    for (int m = 0; m < 2; ++m) {
        #pragma unroll
        for (int n = 0; n < 2; ++n) {
            int gcol = bn + wc * 32 + n * 16 + l15;
            float bs = bias[gcol];
            #pragma unroll
            for (int r = 0; r < 4; ++r) {
                int grow = bm + wr * 32 + m * 16 + lk * 4 + r;
                float x = acc[m][n][r];
                float o;
                if constexpr (EPI == 2) {
                    o = x + bs + res[(size_t)grow * N + gcol];
                } else if constexpr (EPI == 3) {
                    float t = x + bs;
                    float u = t + 0.044715f * t * t * t;
                    o = 0.5f * t * (1.0f + tanhf(0.7978845608028654f * u));
                } else {
                    o = x + bs + res[(size_t)grow * N + gcol];
                }
                stc(C, (size_t)grow * N + gcol, o);
            }
        }
    }
}

// ----- fused Q+V GEMM: Bt = [QwT;VwT] (1024x512). Q cols -> row-sum of -----
// sigmoid gate into qs[row][h] (deterministic LDS reduce); V cols -> vbuf.
__global__ __launch_bounds__(256) void gemm_qv(const bf16* __restrict__ A,
                                               const bf16* __restrict__ Bt,
                                               const float* __restrict__ qb,
                                               const float* __restrict__ Vb,
                                               float* __restrict__ qs,
                                               float* __restrict__ vbuf)
{
    __shared__ unsigned short As[2][64 * 64];
    __shared__ unsigned short Bs[2][64 * 64];
    __shared__ float qsums[2][64];

    const int K = DIM;
    int tid  = threadIdx.x;
    int lane = tid & 63, wave = tid >> 6;
    int wr = wave >> 1, wc = wave & 1;
    int bm = blockIdx.y * 64, bn = blockIdx.x * 64;
    int l15 = lane & 15, lk = lane >> 4;

    const bf16* gA[2]; const bf16* gB[2];
    #pragma unroll
    for (int it = 0; it < 2; ++it) {
        int e = it * 256 + tid, row = e >> 3, g = e & 7;
        int kc = (g ^ (row & 7)) * 8;
        gA[it] = &A [(size_t)(bm + row) * K + kc];
        gB[it] = &Bt[(size_t)(bn + row) * K + kc];
    }

    f32x4 acc[2][2] = {};
    const int NT = K >> 6;   // 8

    #pragma unroll
    for (int it = 0; it < 2; ++it) {
        gload16(gA[it], &As[0][(it * 256 + tid) * 8]);
        gload16(gB[it], &Bs[0][(it * 256 + tid) * 8]);
    }
    __syncthreads();

    for (int t = 0; t < NT; ++t) {
        int cur = t & 1;
        if (t + 1 < NT) {
            #pragma unroll
            for (int it = 0; it < 2; ++it) {
                gload16(gA[it] + (t + 1) * 64, &As[cur ^ 1][(it * 256 + tid) * 8]);
                gload16(gB[it] + (t + 1) * 64, &Bs[cur ^ 1][(it * 256 + tid) * 8]);
            }
        }
        #pragma unroll
        for (int s = 0; s < 2; ++s) {
            bf16x8 a[2], b[2];
            #pragma unroll
            for (int m = 0; m < 2; ++m) {
                int row = wr * 32 + m * 16 + l15;
                a[m] = *(const bf16x8*)&As[cur][row * 64 + ((s * 4 + lk) ^ (l15 & 7)) * 8];
            }
            #pragma unroll
            for (int n = 0; n < 2; ++n) {
                int row = wc * 32 + n * 16 + l15;
                b[n] = *(const bf16x8*)&Bs[cur][row * 64 + ((s * 4 + lk) ^ (l15 & 7)) * 8];
            }
            #pragma unroll
            for (int m = 0; m < 2; ++m)
                #pragma unroll
                for (int n = 0; n < 2; ++n)
                    acc[m][n] = __builtin_amdgcn_mfma_f32_16x16x32_bf16(a[m], b[n], acc[m][n], 0, 0, 0);
        }
        __syncthreads();
    }

    if (bn < DIM) {
        // Q gate: o = sigmoid(x - exp(qb))/64, reduce over this head's 64 cols
        int h = bn >> 6;
        #pragma unroll
        for (int m = 0; m < 2; ++m) {
            #pragma unroll
            for (int r = 0; r < 4; ++r) {
                float s = 0.f;
                #pragma unroll
                for (int n = 0; n < 2; ++n) {
                    int gcol = bn + wc * 32 + n * 16 + l15;
                    float x = acc[m][n][r] - expf(qb[gcol]);
                    s += (1.0f / (1.0f + expf(-x))) * (1.0f / 64.0f);
                }
                #pragma unroll
                for (int off = 1; off < 16; off <<= 1) s += __shfl_xor(s, off);
                if (l15 == 0)
                    qsums[wc][wr * 32 + m * 16 + lk * 4 + r] = s;
            }
        }
        __syncthreads();
        if (tid < 64)
            qs[(size_t)(bm + tid) * NH + h] = qsums[0][tid] + qsums[1][tid];
    } else {
        #pragma unroll
        for (int m = 0; m < 2; ++m) {
            #pragma unroll
            for (int n = 0; n < 2; ++n) {
                int gcol = bn - DIM + wc * 32 + n * 16 + l15;
                float bs = Vb[gcol];
                #pragma unroll
                for (int r = 0; r < 4; ++r) {
                    int grow = bm + wr * 32 + m * 16 + lk * 4 + r;
                    vbuf[(size_t)grow * DIM + gcol] = acc[m][n][r] + bs;
                }
            }
        }
    }
}

// ---- W^T partials: WT[bh][hd][d] = sum_t v[b,t,h,hd] * time[t,h,d] --------
__global__ __launch_bounds__(256) void wpart_kernel(const float* __restrict__ v,
                                                    const bf16* __restrict__ timef,
                                                    float* __restrict__ wpart)
{
    int bh = blockIdx.x;          // 0..15
    int kc = blockIdx.y;          // 0..KCH-1
    int b = bh >> 3, h = bh & 7;
    int hd = threadIdx.x & 63, dg = threadIdx.x >> 6;

    float acc[32] = {};
    int t0 = kc * TCH;
    #pragma unroll 4
    for (int t = t0; t < t0 + TCH; ++t) {
        float vv = v[((size_t)(b * LSEQ + t)) * DIM + h * HDIM + hd];
        const bf16* tp = timef + ((size_t)t * NH + h) * TF + dg * 32;
        bf16x8 tv[4];
        #pragma unroll
        for (int q = 0; q < 4; ++q) tv[q] = *(const bf16x8*)&tp[q * 8];
        #pragma unroll
        for (int q = 0; q < 4; ++q)
            #pragma unroll
            for (int j = 0; j < 8; ++j)
                acc[q * 8 + j] = fmaf((float)tv[q][j], vv, acc[q * 8 + j]);
    }
    float* wp = wpart + ((size_t)(kc * 16 + bh)) * (TF * HDIM) + (size_t)hd * TF + dg * 32;
    #pragma unroll
    for (int q = 0; q < 8; ++q) {
        float4 o = {acc[q * 4], acc[q * 4 + 1], acc[q * 4 + 2], acc[q * 4 + 3]};
        ((float4*)wp)[q] = o;
    }
}

__global__ __launch_bounds__(256) void wred_kernel(const float* __restrict__ wpart,
                                                   bf16* __restrict__ WT)
{
    int i = blockIdx.x * 256 + threadIdx.x;   // < 131072
    float s = 0.f;
    #pragma unroll
    for (int kc = 0; kc < KCH; ++kc)
        s += wpart[(size_t)kc * 131072 + i];
    WT[i] = __float2bfloat16(s);
}

// ---- comb[b,l,h,:] = qs[l,h]*mask[l] * (time[l,h,:] @ WT[bh]^T), MFMA ------
__global__ __launch_bounds__(256) void comb_mfma(const bf16* __restrict__ timef,
                                                 const bf16* __restrict__ WT,
                                                 const float* __restrict__ qs,
                                                 const float* __restrict__ mask,
                                                 bf16* __restrict__ comb)
{
    int bh = blockIdx.x;
    int b = bh >> 3, h = bh & 7;
    int lane = threadIdx.x & 63, wave = threadIdx.x >> 6;
    int l15 = lane & 15, lk = lane >> 4;
    int lbase = blockIdx.y * 256 + wave * 64;

    const bf16* wt = WT + (size_t)bh * (HDIM * TF);

    f32x4 acc[4][4] = {};
    #pragma unroll
    for (int ks = 0; ks < 4; ++ks) {
        int kt = ks * 32;
        bf16x8 a[4], bf[4];
        #pragma unroll
        for (int m = 0; m < 4; ++m) {
            int l = lbase + m * 16 + l15;
            a[m] = *(const bf16x8*)&timef[((size_t)l * NH + h) * TF + kt + lk * 8];
        }
        #pragma unroll
        for (int n = 0; n < 4; ++n)
            bf[n] = *(const bf16x8*)&wt[(size_t)(n * 16 + l15) * TF + kt + lk * 8];
        #pragma unroll
        for (int m = 0; m < 4; ++m)
            #pragma unroll
            for (int n = 0; n < 4; ++n)
                acc[m][n] = __builtin_amdgcn_mfma_f32_16x16x32_bf16(a[m], bf[n], acc[m][n], 0, 0, 0);
    }

    #pragma unroll
    for (int m = 0; m < 4; ++m) {
        #pragma unroll
        for (int r = 0; r < 4; ++r) {
            int l = lbase + m * 16 + lk * 4 + r;
            int row = b * LSEQ + l;
            float q = qs[(size_t)row * NH + h] * mask[row];
            #pragma unroll
            for (int n = 0; n < 4; ++n) {
                int hd = n * 16 + l15;
                comb[(size_t)row * DIM + h * HDIM + hd] =
                    __float2bfloat16(q * acc[m][n][r]);
            }
        }
    }
}

// ---------------- LayerNorm over last dim (512) ----------------
template<int WB>
__global__ __launch_bounds__(256) void ln_kernel(const float* __restrict__ X,
                                                 const float* __restrict__ g,
                                                 const float* __restrict__ bta,
                                                 float* __restrict__ outf,
                                                 bf16* __restrict__ outb)
{
    int row = blockIdx.x;
    const float* x = X + (size_t)row * DIM;
    float v0 = x[threadIdx.x], v1 = x[threadIdx.x + 256];
    float s = v0 + v1, s2 = v0 * v0 + v1 * v1;
    #pragma unroll
    for (int off = 1; off < 64; off <<= 1) {
        s  += __shfl_xor(s,  off);
        s2 += __shfl_xor(s2, off);
    }
    __shared__ float sh[2][4];
    int wave = threadIdx.x >> 6, lane = threadIdx.x & 63;
    if (lane == 0) { sh[0][wave] = s; sh[1][wave] = s2; }
    __syncthreads();
    s  = sh[0][0] + sh[0][1] + sh[0][2] + sh[0][3];
    s2 = sh[1][0] + sh[1][1] + sh[1][2] + sh[1][3];
    float mu  = s * (1.0f / DIM);
    float var = s2 * (1.0f / DIM) - mu * mu;
    float inv = rsqrtf(var + 1e-5f);
    int c0 = threadIdx.x, c1 = threadIdx.x + 256;
    float o0 = (v0 - mu) * inv * g[c0] + bta[c0];
    float o1 = (v1 - mu) * inv * g[c1] + bta[c1];
    outf[(size_t)row * DIM + c0] = o0;
    outf[(size_t)row * DIM + c1] = o1;
    if constexpr (WB) {
        outb[(size_t)row * DIM + c0] = __float2bfloat16(o0);
        outb[(size_t)row * DIM + c1] = __float2bfloat16(o1);
    }
}

extern "C" void kernel_launch(void* const* d_in, const int* in_sizes, int n_in,
                              void* d_out, int out_size, void* d_ws, size_t ws_size,
                              hipStream_t stream)
{
    const float* tensor = (const float*)d_in[0];
    const float* mask   = (const float*)d_in[1];
    const float* tang   = (const float*)d_in[2];
    const float* htd    = (const float*)d_in[3];
    const float* Qw     = (const float*)d_in[4];
    const float* qb     = (const float*)d_in[5];
    // d_in[6], d_in[7] (Kw, Kb) dead code
    const float* Vw     = (const float*)d_in[8];
    const float* Vb     = (const float*)d_in[9];
    const float* Ow     = (const float*)d_in[10];
    const float* Ob     = (const float*)d_in[11];
    const float* g1     = (const float*)d_in[12];
    const float* b1     = (const float*)d_in[13];
    const float* Win    = (const float*)d_in[14];
    const float* bin    = (const float*)d_in[15];
    const float* Wout   = (const float*)d_in[16];
    const float* bout   = (const float*)d_in[17];
    const float* g2     = (const float*)d_in[18];
    const float* b2     = (const float*)d_in[19];
    float* out = (float*)d_out;

    float* ws = (float*)d_ws;
    // f32-unit offsets. Lifetimes (written -> last read):
    //   vbuf    [0,        2097152)  v: s3->s4;   preLN1: s7->s8
    //   actb    [0,        3145728)  bf16 FFN act: s9->s10
    //   tensorb [2097152,  3145728)  s1->s3; combb reuse: s6->s7
    //   timefb  [3145728,  4194304)  s1->s6
    //   interb  [4194304,  5242880)  s8->s9
    //   wpart   [5242880,  9437184)  s4->s5  (32 x 131072)
    //   buf5    [5242880,  7340032)  preLN2: s10->s11
    //   inter   [7340032,  9437184)  f32: s8->s10
    //   WTb     [9437184,  9502720)  bf16: s5->s6
    //   qs      [9502720,  9535488)  f32:  s3->s6
    //   QVwT    [9535488,  9797632)  bf16 [1024][512]: s2->s3
    //   OwT     [9797632,  9928704)  s2->s7
    //   WinT    [9928704, 10321920)  s2->s9
    //   WoutT   [10321920,10715136)  s2->s10
    // peak = 10715136 f32 = 42.9 MB
    float* vbuf   = ws + 0;
    bf16*  actb   = (bf16*)(ws + 0);
    bf16*  tensorb= (bf16*)(ws + 2097152);
    bf16*  combb  = tensorb;
    bf16*  timefb = (bf16*)(ws + 3145728);
    bf16*  interb = (bf16*)(ws + 4194304);
    float* wpart  = ws + 5242880;
    float* buf5   = ws + 5242880;
    float* inter  = ws + 7340032;
    bf16*  WTb    = (bf16*)(ws + 9437184);
    float* qs     = ws + 9502720;
    bf16*  QVwT   = (bf16*)(ws + 9535488);
    bf16*  QwT    = QVwT;                         // rows 0..511
    bf16*  VwT    = QVwT + (size_t)512 * 512;     // rows 512..1023
    bf16*  OwT    = (bf16*)(ws + 9797632);
    bf16*  WinT   = (bf16*)(ws + 9928704);
    bf16*  WoutT  = (bf16*)(ws + 10321920);

    // 1. prep: tensor->bf16 + time features
    prep_kernel<<<6144, 256, 0, stream>>>(tensor, tang, htd, tensorb, timefb);
    // 2. weight transposes (QwT/VwT land concatenated as QVwT)
    transpose_all<<<2304, 256, 0, stream>>>(Qw, Vw, Ow, Win, Wout, QwT, VwT, OwT, WinT, WoutT);
    // 3. fused Q+V GEMM: qs row-sums + vbuf
    gemm_qv<<<dim3(16, 64), 256, 0, stream>>>(tensorb, QVwT, qb, Vb, qs, vbuf);
    // 4. WT partials (split-K 32)
    wpart_kernel<<<dim3(16, KCH), 256, 0, stream>>>(vbuf, timefb, wpart);
    // 5. reduce -> WT bf16
    wred_kernel<<<512, 256, 0, stream>>>(wpart, WTb);
    // 6. comb via MFMA
    comb_mfma<<<dim3(16, 8), 256, 0, stream>>>(timefb, WTb, qs, mask, combb);
    // 7. attn_out + residual(tensor) -> preLN1
    gemm64<2, float><<<dim3(8, 64), 256, 0, stream>>>(combb, OwT, Ob, tensor, vbuf, ROWS, DIM, DIM);
    // 8. LN1 -> inter f32 + interb bf16
    ln_kernel<1><<<ROWS, 256, 0, stream>>>(vbuf, g1, b1, inter, interb);
    // 9. FFN in + gelu -> bf16
    gemm64<3, bf16><<<dim3(24, 64), 256, 0, stream>>>(interb, WinT, bin, nullptr, actb, ROWS, LIND, DIM);
    // 10. FFN out + residual(inter)
    gemm64<4, float><<<dim3(8, 64), 256, 0, stream>>>(actb, WoutT, bout, inter, buf5, ROWS, DIM, LIND);
    // 11. LN2 -> f32 output
    ln_kernel<0><<<ROWS, 256, 0, stream>>>(buf5, g2, b2, out, nullptr);
}